// Round 1
// baseline (9894.898 us; speedup 1.0000x reference)
//
#include <hip/hip_runtime.h>
#include <cstdint>
#include <cstddef>

// Problem constants (from reference)
#define PN1   10000
#define PN2   10000
#define FIN   128
#define HID   128
#define NH    8
#define HD    16
#define NLAY  2
#define NE12  320000
#define NE21  320000
#define NEF   500000

// ---------- helpers ----------
__device__ __forceinline__ unsigned fkey(float f) {
  unsigned u = __float_as_uint(f);
  return (u & 0x80000000u) ? ~u : (u | 0x80000000u);
}
__device__ __forceinline__ float funkey(unsigned u) {
  unsigned b = (u & 0x80000000u) ? (u & 0x7FFFFFFFu) : ~u;
  return __uint_as_float(b);
}
__device__ __forceinline__ void atomAddF(float* p, float v) {
  unsafeAtomicAdd(p, v);   // hardware global_atomic_add_f32 on gfx950
}

// ---------- GEMM: Y[N,128] = act(X[N,128] @ W[128,128] + b) ----------
// mode 0: relu   mode 1: plain   mode 2: blend-skip + concat-write
#define GEMM_ROWS 16
__launch_bounds__(256, 2)
__global__ void gemm128(const float* __restrict__ X, const float* __restrict__ W,
                        const float* __restrict__ bias, float* __restrict__ Y,
                        int N, int mode, const float* __restrict__ skip,
                        float* __restrict__ catout, int catoff)
{
  __shared__ float sW[64 * 128];          // one 64-row K-chunk of W
  __shared__ float sX[GEMM_ROWS][132];    // +4 pad: conflict-free broadcast
  const int tid = threadIdx.x;
  const int rowbase = blockIdx.x * GEMM_ROWS;

  // stage X tile (full K = 128)
#pragma unroll
  for (int i = 0; i < 2; ++i) {
    int idx = tid + i * 256;              // 0..511 float4s
    int r = idx >> 5;
    int c4 = (idx & 31) << 2;
    int gr = rowbase + r;
    float4 v = make_float4(0.f, 0.f, 0.f, 0.f);
    if (gr < N) v = *(const float4*)(X + (size_t)gr * 128 + c4);
    sX[r][c4 + 0] = v.x; sX[r][c4 + 1] = v.y;
    sX[r][c4 + 2] = v.z; sX[r][c4 + 3] = v.w;
  }

  const int r0 = (tid >> 5) << 1;         // 2 rows per thread
  const int cc = (tid & 31) << 2;         // 4 consecutive cols per thread
  float acc[2][4] = {{0.f,0.f,0.f,0.f},{0.f,0.f,0.f,0.f}};

  for (int kc = 0; kc < 128; kc += 64) {
    __syncthreads();                      // sX ready / sW safe to overwrite
#pragma unroll
    for (int i = 0; i < 8; ++i) {         // 64*128 floats = 2048 float4
      int idx = tid + i * 256;
      *(float4*)&sW[idx << 2] = *(const float4*)(W + (size_t)kc * 128 + (idx << 2));
    }
    __syncthreads();
#pragma unroll 8
    for (int k = 0; k < 64; ++k) {
      const float4 w = *(const float4*)&sW[(k << 7) + cc];
      const float x0 = sX[r0][kc + k];
      const float x1 = sX[r0 + 1][kc + k];
      acc[0][0] = fmaf(x0, w.x, acc[0][0]); acc[0][1] = fmaf(x0, w.y, acc[0][1]);
      acc[0][2] = fmaf(x0, w.z, acc[0][2]); acc[0][3] = fmaf(x0, w.w, acc[0][3]);
      acc[1][0] = fmaf(x1, w.x, acc[1][0]); acc[1][1] = fmaf(x1, w.y, acc[1][1]);
      acc[1][2] = fmaf(x1, w.z, acc[1][2]); acc[1][3] = fmaf(x1, w.w, acc[1][3]);
    }
  }

  const float4 b4 = *(const float4*)(bias + cc);
  float beta = 0.f;
  if (mode == 2) beta = 1.0f / (1.0f + expf(-skip[0]));
#pragma unroll
  for (int i = 0; i < 2; ++i) {
    int row = rowbase + r0 + i;
    if (row >= N) continue;
    float4 t = make_float4(acc[i][0] + b4.x, acc[i][1] + b4.y,
                           acc[i][2] + b4.z, acc[i][3] + b4.w);
    if (mode == 0) {
      t.x = fmaxf(t.x, 0.f); t.y = fmaxf(t.y, 0.f);
      t.z = fmaxf(t.z, 0.f); t.w = fmaxf(t.w, 0.f);
    } else if (mode == 2) {
      const float4 xo = *(const float4*)(Y + (size_t)row * 128 + cc);
      t.x = beta * t.x + (1.f - beta) * xo.x;
      t.y = beta * t.y + (1.f - beta) * xo.y;
      t.z = beta * t.z + (1.f - beta) * xo.z;
      t.w = beta * t.w + (1.f - beta) * xo.w;
      *(float4*)(catout + (size_t)row * 256 + catoff + cc) = t;
    }
    *(float4*)(Y + (size_t)row * 128 + cc) = t;
  }
}

// ---------- fold per-head relation matrix into weight+bias ----------
// Wf[:,h*16+e] = sum_d W[:,h*16+d]*rel[h,d,e];  row 128 handles the bias.
__global__ void fuse_rel(const float* __restrict__ W, const float* __restrict__ b,
                         const float* __restrict__ rel,
                         float* __restrict__ Wf, float* __restrict__ bf)
{
  int idx = blockIdx.x * 256 + threadIdx.x;
  if (idx >= 129 * 128) return;
  int row = idx >> 7, col = idx & 127;
  int h = col >> 4, e = col & 15;
  const float* rr = rel + h * 256;                       // [d][e], stride 16
  const float* src = (row < 128) ? (W + (size_t)row * 128 + h * 16) : (b + h * 16);
  float acc = 0.f;
#pragma unroll
  for (int d = 0; d < 16; ++d) acc = fmaf(src[d], rr[d * 16 + e], acc);
  if (row < 128) Wf[(size_t)row * 128 + col] = acc;
  else           bf[col] = acc;
}

// ---------- edge pass A: alpha + segment max ----------
__global__ void edge_alpha(const int* __restrict__ src, const int* __restrict__ dst,
                           const float* __restrict__ q, const float* __restrict__ ke,
                           const float* __restrict__ prel, int E,
                           float* __restrict__ alpha, unsigned* __restrict__ mkey)
{
  int t = blockIdx.x * 256 + threadIdx.x;
  if (t >= E * NH) return;
  int e = t >> 3, h = t & 7;
  int s_ = src[e], d_ = dst[e];
  const float4* qa = (const float4*)(q  + (size_t)d_ * 128 + h * 16);
  const float4* ka = (const float4*)(ke + (size_t)s_ * 128 + h * 16);
  float a = 0.f;
#pragma unroll
  for (int i = 0; i < 4; ++i) {
    float4 qv = qa[i], kv = ka[i];
    a = fmaf(qv.x, kv.x, a); a = fmaf(qv.y, kv.y, a);
    a = fmaf(qv.z, kv.z, a); a = fmaf(qv.w, kv.w, a);
  }
  a *= prel[h] * 0.25f;                  // p_rel / sqrt(D), D = 16
  alpha[t] = a;
  atomicMax(&mkey[(size_t)d_ * NH + h], fkey(a));
}

// ---------- edge pass B: exp + segment sum ----------
__global__ void edge_expsum(const int* __restrict__ dst, float* __restrict__ alpha,
                            const unsigned* __restrict__ mkey,
                            float* __restrict__ esum, int E)
{
  int t = blockIdx.x * 256 + threadIdx.x;
  if (t >= E * NH) return;
  int e = t >> 3, h = t & 7;
  int d_ = dst[e];
  float m = funkey(mkey[(size_t)d_ * NH + h]);
  float ex = expf(alpha[t] - m);
  alpha[t] = ex;                          // in-place: alpha now holds exp()
  atomAddF(&esum[(size_t)d_ * NH + h], ex);
}

// ---------- edge pass C: weighted scatter of ve ----------
__global__ void edge_agg(const int* __restrict__ src, const int* __restrict__ dst,
                         const float* __restrict__ ebuf, const float* __restrict__ esum,
                         const float* __restrict__ ve, float* __restrict__ agg, int E)
{
  int t = blockIdx.x * 256 + threadIdx.x;
  if (t >= E * NH) return;
  int e = t >> 3, h = t & 7;
  int s_ = src[e], d_ = dst[e];
  float w = ebuf[t] / (esum[(size_t)d_ * NH + h] + 1e-16f);
  const float4* v4 = (const float4*)(ve + (size_t)s_ * 128 + h * 16);
  float* out = agg + (size_t)d_ * 128 + h * 16;
#pragma unroll
  for (int i = 0; i < 4; ++i) {
    float4 v = v4[i];
    atomAddF(out + 4 * i + 0, w * v.x);
    atomAddF(out + 4 * i + 1, w * v.y);
    atomAddF(out + 4 * i + 2, w * v.z);
    atomAddF(out + 4 * i + 3, w * v.w);
  }
}

// ---------- exact gelu, in place ----------
__global__ void gelu_k(float* __restrict__ x, int n4)
{
  int i = blockIdx.x * 256 + threadIdx.x;
  if (i >= n4) return;
  float4 v = ((float4*)x)[i];
  v.x = 0.5f * v.x * (1.f + erff(v.x * 0.70710678118654752f));
  v.y = 0.5f * v.y * (1.f + erff(v.y * 0.70710678118654752f));
  v.z = 0.5f * v.z * (1.f + erff(v.z * 0.70710678118654752f));
  v.w = 0.5f * v.w * (1.f + erff(v.w * 0.70710678118654752f));
  ((float4*)x)[i] = v;
}

// ---------- readout: y[e] = dot(Em[mi[e]], Ed[di[e]]) over 256 ----------
__launch_bounds__(256)
__global__ void edge_dot(const int* __restrict__ mi, const int* __restrict__ di,
                         const float* __restrict__ Em, const float* __restrict__ Ed,
                         float* __restrict__ y, int E)
{
  int t = blockIdx.x * 256 + threadIdx.x;
  int e = t >> 4;                          // 16 lanes per edge
  int l = t & 15;
  if (e >= E) return;
  int m = mi[e], d = di[e];
  const float4* A = (const float4*)(Em + (size_t)m * 256);
  const float4* B = (const float4*)(Ed + (size_t)d * 256);
  float acc = 0.f;
#pragma unroll
  for (int i = 0; i < 4; ++i) {
    float4 a = A[i * 16 + l];
    float4 b = B[i * 16 + l];
    acc = fmaf(a.x, b.x, acc); acc = fmaf(a.y, b.y, acc);
    acc = fmaf(a.z, b.z, acc); acc = fmaf(a.w, b.w, acc);
  }
#pragma unroll
  for (int off = 8; off >= 1; off >>= 1) acc += __shfl_xor(acc, off, 64);
  if (l == 0) y[e] = acc;
}

// ---------- launch ----------
extern "C" void kernel_launch(void* const* d_in, const int* in_sizes, int n_in,
                              void* d_out, int out_size, void* d_ws, size_t ws_size,
                              hipStream_t stream)
{
  const float* x_n1  = (const float*)d_in[0];
  const float* x_n2  = (const float*)d_in[1];
  const float* W_in1 = (const float*)d_in[2];
  const float* b_in1 = (const float*)d_in[3];
  const float* W_in2 = (const float*)d_in[4];
  const float* b_in2 = (const float*)d_in[5];
  const float* Wk_n1 = (const float*)d_in[6];
  const float* bk_n1 = (const float*)d_in[7];
  const float* Wq_n1 = (const float*)d_in[8];
  const float* bq_n1 = (const float*)d_in[9];
  const float* Wv_n1 = (const float*)d_in[10];
  const float* bv_n1 = (const float*)d_in[11];
  const float* Wa_n1 = (const float*)d_in[12];
  const float* ba_n1 = (const float*)d_in[13];
  const float* skip_n1 = (const float*)d_in[14];
  const float* Wk_n2 = (const float*)d_in[15];
  const float* bk_n2 = (const float*)d_in[16];
  const float* Wq_n2 = (const float*)d_in[17];
  const float* bq_n2 = (const float*)d_in[18];
  const float* Wv_n2 = (const float*)d_in[19];
  const float* bv_n2 = (const float*)d_in[20];
  const float* Wa_n2 = (const float*)d_in[21];
  const float* ba_n2 = (const float*)d_in[22];
  const float* skip_n2 = (const float*)d_in[23];
  const float* a_rel_12 = (const float*)d_in[24];
  const float* m_rel_12 = (const float*)d_in[25];
  const float* p_rel_12 = (const float*)d_in[26];
  const float* a_rel_21 = (const float*)d_in[27];
  const float* m_rel_21 = (const float*)d_in[28];
  const float* p_rel_21 = (const float*)d_in[29];
  const int*   ei_12 = (const int*)d_in[30];
  const int*   ei_21 = (const int*)d_in[31];
  const int*   edge_index = (const int*)d_in[32];
  float* y = (float*)d_out;

  // ---- workspace carve-up (floats) ----
  const size_t NF = (size_t)PN1 * 128;   // 1,280,000
  float* ws = (float*)d_ws;
  float* x1   = ws + 0 * NF;
  float* x2   = ws + 1 * NF;
  float* q1   = ws + 2 * NF;
  float* ke1  = ws + 3 * NF;
  float* ve1  = ws + 4 * NF;
  float* q2   = ws + 5 * NF;
  float* ke2  = ws + 6 * NF;
  float* ve2  = ws + 7 * NF;
  float* agg1 = ws + 8 * NF;
  float* agg2 = ws + 9 * NF;
  float* Em   = ws + 10 * NF;            // [N1, 256]
  float* Ed   = ws + 12 * NF;            // [N2, 256]
  float* alpha = ws + 14 * NF;           // [E, 8] (max E fits: 2.56M floats)
  unsigned* mkey = (unsigned*)(ws + 16 * NF);           // [N, 8]
  float* esum = ws + 16 * NF + 98304;                    // [N, 8]
  float* WkF1 = ws + 16 * NF + 196608;  float* bkF1 = WkF1 + 16384;
  float* WvF1 = WkF1 + 24576;           float* bvF1 = WvF1 + 16384;
  float* WkF2 = WvF1 + 24576;           float* bkF2 = WkF2 + 16384;
  float* WvF2 = WkF2 + 24576;           float* bvF2 = WvF2 + 16384;

  const int GEMM_BLOCKS = (PN1 + GEMM_ROWS - 1) / GEMM_ROWS;   // 625
  const int EB12 = (NE12 * NH + 255) / 256;                    // 10000
  const int EB21 = (NE21 * NH + 255) / 256;
  const int FUSE_B = (129 * 128 + 255) / 256;                  // 65
  const int GELU_B = ((int)(NF / 4) + 255) / 256;              // 1250

  // input projections + relu
  gemm128<<<GEMM_BLOCKS, 256, 0, stream>>>(x_n1, W_in1, b_in1, x1, PN1, 0, nullptr, nullptr, 0);
  gemm128<<<GEMM_BLOCKS, 256, 0, stream>>>(x_n2, W_in2, b_in2, x2, PN2, 0, nullptr, nullptr, 0);

  for (int l = 0; l < NLAY; ++l) {
    const float* Wk1 = Wk_n1 + (size_t)l * 16384;  const float* bk1 = bk_n1 + l * 128;
    const float* Wq1 = Wq_n1 + (size_t)l * 16384;  const float* bq1 = bq_n1 + l * 128;
    const float* Wv1 = Wv_n1 + (size_t)l * 16384;  const float* bv1 = bv_n1 + l * 128;
    const float* Wa1 = Wa_n1 + (size_t)l * 16384;  const float* ba1 = ba_n1 + l * 128;
    const float* Wk2 = Wk_n2 + (size_t)l * 16384;  const float* bk2 = bk_n2 + l * 128;
    const float* Wq2 = Wq_n2 + (size_t)l * 16384;  const float* bq2 = bq_n2 + l * 128;
    const float* Wv2 = Wv_n2 + (size_t)l * 16384;  const float* bv2 = bv_n2 + l * 128;
    const float* Wa2 = Wa_n2 + (size_t)l * 16384;  const float* ba2 = ba_n2 + l * 128;

    // fold relation matrices into K/V weights
    fuse_rel<<<FUSE_B, 256, 0, stream>>>(Wk1, bk1, a_rel_12 + (size_t)l * 2048, WkF1, bkF1);
    fuse_rel<<<FUSE_B, 256, 0, stream>>>(Wv1, bv1, m_rel_12 + (size_t)l * 2048, WvF1, bvF1);
    fuse_rel<<<FUSE_B, 256, 0, stream>>>(Wk2, bk2, a_rel_21 + (size_t)l * 2048, WkF2, bkF2);
    fuse_rel<<<FUSE_B, 256, 0, stream>>>(Wv2, bv2, m_rel_21 + (size_t)l * 2048, WvF2, bvF2);

    // node projections
    gemm128<<<GEMM_BLOCKS, 256, 0, stream>>>(x1, WkF1, bkF1, ke1, PN1, 1, nullptr, nullptr, 0);
    gemm128<<<GEMM_BLOCKS, 256, 0, stream>>>(x1, WvF1, bvF1, ve1, PN1, 1, nullptr, nullptr, 0);
    gemm128<<<GEMM_BLOCKS, 256, 0, stream>>>(x1, Wq1, bq1, q1, PN1, 1, nullptr, nullptr, 0);
    gemm128<<<GEMM_BLOCKS, 256, 0, stream>>>(x2, WkF2, bkF2, ke2, PN2, 1, nullptr, nullptr, 0);
    gemm128<<<GEMM_BLOCKS, 256, 0, stream>>>(x2, WvF2, bvF2, ve2, PN2, 1, nullptr, nullptr, 0);
    gemm128<<<GEMM_BLOCKS, 256, 0, stream>>>(x2, Wq2, bq2, q2, PN2, 1, nullptr, nullptr, 0);

    // direction 12: src nodes in n1, dst nodes in n2
    hipMemsetAsync(mkey, 0, (size_t)PN2 * NH * 4, stream);
    hipMemsetAsync(esum, 0, (size_t)PN2 * NH * 4, stream);
    hipMemsetAsync(agg2, 0, NF * 4, stream);
    edge_alpha<<<EB12, 256, 0, stream>>>(ei_12, ei_12 + NE12, q2, ke1,
                                         p_rel_12 + l * NH, NE12, alpha, mkey);
    edge_expsum<<<EB12, 256, 0, stream>>>(ei_12 + NE12, alpha, mkey, esum, NE12);
    edge_agg<<<EB12, 256, 0, stream>>>(ei_12, ei_12 + NE12, alpha, esum, ve1, agg2, NE12);

    // direction 21: src nodes in n2, dst nodes in n1
    hipMemsetAsync(mkey, 0, (size_t)PN1 * NH * 4, stream);
    hipMemsetAsync(esum, 0, (size_t)PN1 * NH * 4, stream);
    hipMemsetAsync(agg1, 0, NF * 4, stream);
    edge_alpha<<<EB21, 256, 0, stream>>>(ei_21, ei_21 + NE21, q1, ke2,
                                         p_rel_21 + l * NH, NE21, alpha, mkey);
    edge_expsum<<<EB21, 256, 0, stream>>>(ei_21 + NE21, alpha, mkey, esum, NE21);
    edge_agg<<<EB21, 256, 0, stream>>>(ei_21, ei_21 + NE21, alpha, esum, ve2, agg1, NE21);

    // gelu (in place) + output projection + skip blend + concat write
    gelu_k<<<GELU_B, 256, 0, stream>>>(agg1, (int)(NF / 4));
    gelu_k<<<GELU_B, 256, 0, stream>>>(agg2, (int)(NF / 4));
    gemm128<<<GEMM_BLOCKS, 256, 0, stream>>>(agg1, Wa1, ba1, x1, PN1, 2, skip_n1 + l, Em, l * 128);
    gemm128<<<GEMM_BLOCKS, 256, 0, stream>>>(agg2, Wa2, ba2, x2, PN2, 2, skip_n2 + l, Ed, l * 128);
  }

  // readout
  const int DOT_B = (NEF * 16 + 255) / 256;   // 31250
  edge_dot<<<DOT_B, 256, 0, stream>>>(edge_index, edge_index + NEF, Em, Ed, y, NEF);
}

// Round 2
// 814.000 us; speedup vs baseline: 12.1559x; 12.1559x over previous
//
#include <hip/hip_runtime.h>
#include <cstdint>
#include <cstddef>

// Problem constants (from reference)
#define PN1   10000
#define PN2   10000
#define FIN   128
#define HID   128
#define NH    8
#define HD    16
#define NLAY  2
#define NE12  320000
#define NE21  320000
#define NEF   500000

// ---------- GEMM: Y[N,128] = act(X[N,128] @ W[128,128] + b) ----------
// mode 0: relu   mode 1: plain   mode 2: blend-skip + concat-write
#define GEMM_ROWS 16
__launch_bounds__(256, 2)
__global__ void gemm128(const float* __restrict__ X, const float* __restrict__ W,
                        const float* __restrict__ bias, float* __restrict__ Y,
                        int N, int mode, const float* __restrict__ skip,
                        float* __restrict__ catout, int catoff)
{
  __shared__ float sW[64 * 128];          // one 64-row K-chunk of W
  __shared__ float sX[GEMM_ROWS][132];    // +4 pad: conflict-free broadcast
  const int tid = threadIdx.x;
  const int rowbase = blockIdx.x * GEMM_ROWS;

  // stage X tile (full K = 128)
#pragma unroll
  for (int i = 0; i < 2; ++i) {
    int idx = tid + i * 256;              // 0..511 float4s
    int r = idx >> 5;
    int c4 = (idx & 31) << 2;
    int gr = rowbase + r;
    float4 v = make_float4(0.f, 0.f, 0.f, 0.f);
    if (gr < N) v = *(const float4*)(X + (size_t)gr * 128 + c4);
    sX[r][c4 + 0] = v.x; sX[r][c4 + 1] = v.y;
    sX[r][c4 + 2] = v.z; sX[r][c4 + 3] = v.w;
  }

  const int r0 = (tid >> 5) << 1;         // 2 rows per thread
  const int cc = (tid & 31) << 2;         // 4 consecutive cols per thread
  float acc[2][4] = {{0.f,0.f,0.f,0.f},{0.f,0.f,0.f,0.f}};

  for (int kc = 0; kc < 128; kc += 64) {
    __syncthreads();                      // sX ready / sW safe to overwrite
#pragma unroll
    for (int i = 0; i < 8; ++i) {         // 64*128 floats = 2048 float4
      int idx = tid + i * 256;
      *(float4*)&sW[idx << 2] = *(const float4*)(W + (size_t)kc * 128 + (idx << 2));
    }
    __syncthreads();
#pragma unroll 8
    for (int k = 0; k < 64; ++k) {
      const float4 w = *(const float4*)&sW[(k << 7) + cc];
      const float x0 = sX[r0][kc + k];
      const float x1 = sX[r0 + 1][kc + k];
      acc[0][0] = fmaf(x0, w.x, acc[0][0]); acc[0][1] = fmaf(x0, w.y, acc[0][1]);
      acc[0][2] = fmaf(x0, w.z, acc[0][2]); acc[0][3] = fmaf(x0, w.w, acc[0][3]);
      acc[1][0] = fmaf(x1, w.x, acc[1][0]); acc[1][1] = fmaf(x1, w.y, acc[1][1]);
      acc[1][2] = fmaf(x1, w.z, acc[1][2]); acc[1][3] = fmaf(x1, w.w, acc[1][3]);
    }
  }

  const float4 b4 = *(const float4*)(bias + cc);
  float beta = 0.f;
  if (mode == 2) beta = 1.0f / (1.0f + expf(-skip[0]));
#pragma unroll
  for (int i = 0; i < 2; ++i) {
    int row = rowbase + r0 + i;
    if (row >= N) continue;
    float4 t = make_float4(acc[i][0] + b4.x, acc[i][1] + b4.y,
                           acc[i][2] + b4.z, acc[i][3] + b4.w);
    if (mode == 0) {
      t.x = fmaxf(t.x, 0.f); t.y = fmaxf(t.y, 0.f);
      t.z = fmaxf(t.z, 0.f); t.w = fmaxf(t.w, 0.f);
    } else if (mode == 2) {
      const float4 xo = *(const float4*)(Y + (size_t)row * 128 + cc);
      t.x = beta * t.x + (1.f - beta) * xo.x;
      t.y = beta * t.y + (1.f - beta) * xo.y;
      t.z = beta * t.z + (1.f - beta) * xo.z;
      t.w = beta * t.w + (1.f - beta) * xo.w;
      *(float4*)(catout + (size_t)row * 256 + catoff + cc) = t;
    }
    *(float4*)(Y + (size_t)row * 128 + cc) = t;
  }
}

// ---------- fold per-head relation matrix into weight+bias ----------
__global__ void fuse_rel(const float* __restrict__ W, const float* __restrict__ b,
                         const float* __restrict__ rel,
                         float* __restrict__ Wf, float* __restrict__ bf)
{
  int idx = blockIdx.x * 256 + threadIdx.x;
  if (idx >= 129 * 128) return;
  int row = idx >> 7, col = idx & 127;
  int h = col >> 4, e = col & 15;
  const float* rr = rel + h * 256;                       // [d][e], stride 16
  const float* src = (row < 128) ? (W + (size_t)row * 128 + h * 16) : (b + h * 16);
  float acc = 0.f;
#pragma unroll
  for (int d = 0; d < 16; ++d) acc = fmaf(src[d], rr[d * 16 + e], acc);
  if (row < 128) Wf[(size_t)row * 128 + col] = acc;
  else           bf[col] = acc;
}

// ---------- CSR build: histogram ----------
__global__ void csr_hist(const int* __restrict__ dst, int* __restrict__ deg, int E)
{
  int e = blockIdx.x * 256 + threadIdx.x;
  if (e < E) atomicAdd(&deg[dst[e]], 1);
}

// ---------- CSR build: exclusive scan over N bins (single block) ----------
__global__ void csr_scan(const int* __restrict__ deg, int* __restrict__ rowptr,
                         int* __restrict__ cursor, int N, int E)
{
  __shared__ int part[256];
  const int t = threadIdx.x;
  const int chunk = (N + 255) / 256;
  const int b = t * chunk;
  const int e = (b + chunk < N) ? b + chunk : N;
  int s = 0;
  for (int i = b; i < e; ++i) s += deg[i];
  part[t] = s;
  __syncthreads();
  if (t == 0) {
    int run = 0;
    for (int i = 0; i < 256; ++i) { int v = part[i]; part[i] = run; run += v; }
  }
  __syncthreads();
  int run = part[t];
  for (int i = b; i < e; ++i) {
    rowptr[i] = run; cursor[i] = run; run += deg[i];
  }
  if (t == 0) rowptr[N] = E;
}

// ---------- CSR build: scatter src by dst ----------
__global__ void csr_scatter(const int* __restrict__ src, const int* __restrict__ dst,
                            int* __restrict__ cursor, int* __restrict__ csr_src, int E)
{
  int e = blockIdx.x * 256 + threadIdx.x;
  if (e >= E) return;
  int pos = atomicAdd(&cursor[dst[e]], 1);
  csr_src[pos] = src[e];
}

// ---------- fused gather attention (online softmax) + gelu ----------
// one block per dst node; one thread per output channel (128 = H*D)
__launch_bounds__(128)
__global__ void attn_gather(const int* __restrict__ rowptr, const int* __restrict__ csr_src,
                            const float* __restrict__ q, const float* __restrict__ ke,
                            const float* __restrict__ ve, const float* __restrict__ prel,
                            float* __restrict__ agg)
{
  const int d = blockIdx.x;
  const int c = threadIdx.x;          // channel
  const int h = c >> 4;               // head
  const float qc = q[(size_t)d * 128 + c];
  const float pr = prel[h] * 0.25f;   // p_rel / sqrt(16)
  const int beg = rowptr[d], end = rowptr[d + 1];

  float m = -1e30f, ssum = 0.f, acc = 0.f;
  for (int i = beg; i < end; ++i) {
    const int s = csr_src[i];          // block-uniform -> scalar load
    const float kc = ke[(size_t)s * 128 + c];
    const float vc = ve[(size_t)s * 128 + c];
    float p = qc * kc;                 // 16-lane head reduction (within wave)
    p += __shfl_xor(p, 1); p += __shfl_xor(p, 2);
    p += __shfl_xor(p, 4); p += __shfl_xor(p, 8);
    const float a = p * pr;
    const float nm = fmaxf(m, a);
    const float f  = __expf(m - nm);
    const float ex = __expf(a - nm);
    ssum = ssum * f + ex;
    acc  = acc  * f + ex * vc;
    m = nm;
  }
  float o = acc / (ssum + 1e-16f);
  o = 0.5f * o * (1.f + erff(o * 0.70710678118654752f));   // exact gelu
  agg[(size_t)d * 128 + c] = o;
}

// ---------- readout: y[e] = dot(Em[mi[e]], Ed[di[e]]) over 256 ----------
__launch_bounds__(256)
__global__ void edge_dot(const int* __restrict__ mi, const int* __restrict__ di,
                         const float* __restrict__ Em, const float* __restrict__ Ed,
                         float* __restrict__ y, int E)
{
  int t = blockIdx.x * 256 + threadIdx.x;
  int e = t >> 4;                          // 16 lanes per edge
  int l = t & 15;
  if (e >= E) return;
  int m = mi[e], d = di[e];
  const float4* A = (const float4*)(Em + (size_t)m * 256);
  const float4* B = (const float4*)(Ed + (size_t)d * 256);
  float acc = 0.f;
#pragma unroll
  for (int i = 0; i < 4; ++i) {
    float4 a = A[i * 16 + l];
    float4 b = B[i * 16 + l];
    acc = fmaf(a.x, b.x, acc); acc = fmaf(a.y, b.y, acc);
    acc = fmaf(a.z, b.z, acc); acc = fmaf(a.w, b.w, acc);
  }
#pragma unroll
  for (int off = 8; off >= 1; off >>= 1) acc += __shfl_xor(acc, off, 64);
  if (l == 0) y[e] = acc;
}

// ---------- launch ----------
extern "C" void kernel_launch(void* const* d_in, const int* in_sizes, int n_in,
                              void* d_out, int out_size, void* d_ws, size_t ws_size,
                              hipStream_t stream)
{
  const float* x_n1  = (const float*)d_in[0];
  const float* x_n2  = (const float*)d_in[1];
  const float* W_in1 = (const float*)d_in[2];
  const float* b_in1 = (const float*)d_in[3];
  const float* W_in2 = (const float*)d_in[4];
  const float* b_in2 = (const float*)d_in[5];
  const float* Wk_n1 = (const float*)d_in[6];
  const float* bk_n1 = (const float*)d_in[7];
  const float* Wq_n1 = (const float*)d_in[8];
  const float* bq_n1 = (const float*)d_in[9];
  const float* Wv_n1 = (const float*)d_in[10];
  const float* bv_n1 = (const float*)d_in[11];
  const float* Wa_n1 = (const float*)d_in[12];
  const float* ba_n1 = (const float*)d_in[13];
  const float* skip_n1 = (const float*)d_in[14];
  const float* Wk_n2 = (const float*)d_in[15];
  const float* bk_n2 = (const float*)d_in[16];
  const float* Wq_n2 = (const float*)d_in[17];
  const float* bq_n2 = (const float*)d_in[18];
  const float* Wv_n2 = (const float*)d_in[19];
  const float* bv_n2 = (const float*)d_in[20];
  const float* Wa_n2 = (const float*)d_in[21];
  const float* ba_n2 = (const float*)d_in[22];
  const float* skip_n2 = (const float*)d_in[23];
  const float* a_rel_12 = (const float*)d_in[24];
  const float* m_rel_12 = (const float*)d_in[25];
  const float* p_rel_12 = (const float*)d_in[26];
  const float* a_rel_21 = (const float*)d_in[27];
  const float* m_rel_21 = (const float*)d_in[28];
  const float* p_rel_21 = (const float*)d_in[29];
  const int*   ei_12 = (const int*)d_in[30];
  const int*   ei_21 = (const int*)d_in[31];
  const int*   edge_index = (const int*)d_in[32];
  float* y = (float*)d_out;

  // ---- workspace carve-up ----
  const size_t NF = (size_t)PN1 * 128;   // 1,280,000 floats
  float* ws = (float*)d_ws;
  float* x1   = ws + 0 * NF;
  float* x2   = ws + 1 * NF;
  float* q1   = ws + 2 * NF;
  float* ke1  = ws + 3 * NF;
  float* ve1  = ws + 4 * NF;
  float* q2   = ws + 5 * NF;
  float* ke2  = ws + 6 * NF;
  float* ve2  = ws + 7 * NF;
  float* agg1 = ws + 8 * NF;
  float* agg2 = ws + 9 * NF;
  float* Em   = ws + 10 * NF;            // [N1, 256]
  float* Ed   = ws + 12 * NF;            // [N2, 256]
  float* WkF1 = ws + 14 * NF;            float* bkF1 = WkF1 + 16384;
  float* WvF1 = WkF1 + 16512;            float* bvF1 = WvF1 + 16384;
  float* WkF2 = WvF1 + 16512;            float* bkF2 = WkF2 + 16384;
  float* WvF2 = WkF2 + 16512;            float* bvF2 = WvF2 + 16384;
  int* ip = (int*)(WvF2 + 16512);
  int* rowptr12 = ip;                    // N2+1
  int* csr12    = ip + 10032;            // E12
  int* rowptr21 = ip + 10032 + NE12;     // N1+1
  int* csr21    = ip + 20064 + NE12;     // E21
  int* deg      = ip + 20064 + NE12 + NE21;   // N (scratch)
  int* cursor   = deg + 10000;                // N (scratch)

  const int GEMM_BLOCKS = (PN1 + GEMM_ROWS - 1) / GEMM_ROWS;   // 625
  const int EB12 = (NE12 + 255) / 256;
  const int EB21 = (NE21 + 255) / 256;
  const int FUSE_B = (129 * 128 + 255) / 256;                  // 65

  // ---- CSR build (graph constant across layers: build once per call) ----
  hipMemsetAsync(deg, 0, 10000 * 4, stream);
  csr_hist<<<EB12, 256, 0, stream>>>(ei_12 + NE12, deg, NE12);
  csr_scan<<<1, 256, 0, stream>>>(deg, rowptr12, cursor, PN2, NE12);
  csr_scatter<<<EB12, 256, 0, stream>>>(ei_12, ei_12 + NE12, cursor, csr12, NE12);

  hipMemsetAsync(deg, 0, 10000 * 4, stream);
  csr_hist<<<EB21, 256, 0, stream>>>(ei_21 + NE21, deg, NE21);
  csr_scan<<<1, 256, 0, stream>>>(deg, rowptr21, cursor, PN1, NE21);
  csr_scatter<<<EB21, 256, 0, stream>>>(ei_21, ei_21 + NE21, cursor, csr21, NE21);

  // ---- input projections + relu ----
  gemm128<<<GEMM_BLOCKS, 256, 0, stream>>>(x_n1, W_in1, b_in1, x1, PN1, 0, nullptr, nullptr, 0);
  gemm128<<<GEMM_BLOCKS, 256, 0, stream>>>(x_n2, W_in2, b_in2, x2, PN2, 0, nullptr, nullptr, 0);

  for (int l = 0; l < NLAY; ++l) {
    const float* Wq1 = Wq_n1 + (size_t)l * 16384;  const float* bq1 = bq_n1 + l * 128;
    const float* Wa1 = Wa_n1 + (size_t)l * 16384;  const float* ba1 = ba_n1 + l * 128;
    const float* Wq2 = Wq_n2 + (size_t)l * 16384;  const float* bq2 = bq_n2 + l * 128;
    const float* Wa2 = Wa_n2 + (size_t)l * 16384;  const float* ba2 = ba_n2 + l * 128;

    // fold relation matrices into K/V weights
    fuse_rel<<<FUSE_B, 256, 0, stream>>>(Wk_n1 + (size_t)l * 16384, bk_n1 + l * 128,
                                         a_rel_12 + (size_t)l * 2048, WkF1, bkF1);
    fuse_rel<<<FUSE_B, 256, 0, stream>>>(Wv_n1 + (size_t)l * 16384, bv_n1 + l * 128,
                                         m_rel_12 + (size_t)l * 2048, WvF1, bvF1);
    fuse_rel<<<FUSE_B, 256, 0, stream>>>(Wk_n2 + (size_t)l * 16384, bk_n2 + l * 128,
                                         a_rel_21 + (size_t)l * 2048, WkF2, bkF2);
    fuse_rel<<<FUSE_B, 256, 0, stream>>>(Wv_n2 + (size_t)l * 16384, bv_n2 + l * 128,
                                         m_rel_21 + (size_t)l * 2048, WvF2, bvF2);

    // node projections
    gemm128<<<GEMM_BLOCKS, 256, 0, stream>>>(x1, WkF1, bkF1, ke1, PN1, 1, nullptr, nullptr, 0);
    gemm128<<<GEMM_BLOCKS, 256, 0, stream>>>(x1, WvF1, bvF1, ve1, PN1, 1, nullptr, nullptr, 0);
    gemm128<<<GEMM_BLOCKS, 256, 0, stream>>>(x1, Wq_n1 + (size_t)l * 16384, bq_n1 + l * 128,
                                             q1, PN1, 1, nullptr, nullptr, 0);
    gemm128<<<GEMM_BLOCKS, 256, 0, stream>>>(x2, WkF2, bkF2, ke2, PN2, 1, nullptr, nullptr, 0);
    gemm128<<<GEMM_BLOCKS, 256, 0, stream>>>(x2, WvF2, bvF2, ve2, PN2, 1, nullptr, nullptr, 0);
    gemm128<<<GEMM_BLOCKS, 256, 0, stream>>>(x2, Wq_n2 + (size_t)l * 16384, bq_n2 + l * 128,
                                             q2, PN2, 1, nullptr, nullptr, 0);

    // fused gather attention + gelu (dir 12: dst in n2; dir 21: dst in n1)
    attn_gather<<<PN2, 128, 0, stream>>>(rowptr12, csr12, q2, ke1, ve1,
                                         p_rel_12 + l * NH, agg2);
    attn_gather<<<PN1, 128, 0, stream>>>(rowptr21, csr21, q1, ke2, ve2,
                                         p_rel_21 + l * NH, agg1);

    // output projection + skip blend + concat write
    gemm128<<<GEMM_BLOCKS, 256, 0, stream>>>(agg1, Wa1, ba1, x1, PN1, 2, skip_n1 + l, Em, l * 128);
    gemm128<<<GEMM_BLOCKS, 256, 0, stream>>>(agg2, Wa2, ba2, x2, PN2, 2, skip_n2 + l, Ed, l * 128);
  }

  // readout
  const int DOT_B = (NEF * 16 + 255) / 256;   // 31250
  edge_dot<<<DOT_B, 256, 0, stream>>>(edge_index, edge_index + NEF, Em, Ed, y, NEF);
}

// Round 3
// 573.232 us; speedup vs baseline: 17.2616x; 1.4200x over previous
//
#include <hip/hip_runtime.h>
#include <cstdint>
#include <cstddef>

typedef unsigned short ushort_t;

// Problem constants
#define PN1   10000
#define PN2   10000
#define NH    8
#define NLAY  2
#define NE12  320000
#define NE21  320000
#define NEF   500000

// ---------- bf16 helpers (RNE) ----------
__device__ __forceinline__ unsigned f2bf(float f) {
  union { float f; unsigned u; } v; v.f = f;
  return (v.u + 0x7FFFu + ((v.u >> 16) & 1u)) >> 16;
}
__device__ __forceinline__ float bf2f(unsigned s) {
  union { float f; unsigned u; } v; v.u = s << 16; return v.f;
}

// ---------- dual-type GEMM: Y[N,128] = act(X @ W + b) ----------
// mode 0: relu   mode 2: skip-blend + bf16 concat write
#define GEMM_ROWS 16
__launch_bounds__(256, 2)
__global__ void gemm_dual(const float* __restrict__ X1, const float* __restrict__ W1,
                          const float* __restrict__ b1, float* __restrict__ Y1,
                          const float* __restrict__ X2, const float* __restrict__ W2,
                          const float* __restrict__ b2, float* __restrict__ Y2,
                          int nb1, int mode,
                          const float* __restrict__ skip1, const float* __restrict__ skip2,
                          ushort_t* __restrict__ cat1, ushort_t* __restrict__ cat2, int catoff)
{
  __shared__ float sW[64 * 128];
  __shared__ float sX[GEMM_ROWS][132];
  const int bid = blockIdx.x;
  const bool t2 = bid >= nb1;
  const float* X = t2 ? X2 : X1;  const float* W = t2 ? W2 : W1;
  const float* bias = t2 ? b2 : b1;  float* Y = t2 ? Y2 : Y1;
  const float* skip = t2 ? skip2 : skip1;
  ushort_t* cat = t2 ? cat2 : cat1;
  const int tid = threadIdx.x;
  const int rowbase = (t2 ? bid - nb1 : bid) * GEMM_ROWS;

#pragma unroll
  for (int i = 0; i < 2; ++i) {
    int idx = tid + i * 256;
    int r = idx >> 5, c4 = (idx & 31) << 2;
    float4 v = *(const float4*)(X + (size_t)(rowbase + r) * 128 + c4);
    sX[r][c4 + 0] = v.x; sX[r][c4 + 1] = v.y;
    sX[r][c4 + 2] = v.z; sX[r][c4 + 3] = v.w;
  }

  const int r0 = (tid >> 5) << 1;
  const int cc = (tid & 31) << 2;
  float acc[2][4] = {{0.f,0.f,0.f,0.f},{0.f,0.f,0.f,0.f}};

  for (int kc = 0; kc < 128; kc += 64) {
    __syncthreads();
#pragma unroll
    for (int i = 0; i < 8; ++i) {
      int idx = tid + i * 256;
      *(float4*)&sW[idx << 2] = *(const float4*)(W + (size_t)kc * 128 + (idx << 2));
    }
    __syncthreads();
#pragma unroll 8
    for (int k = 0; k < 64; ++k) {
      const float4 w = *(const float4*)&sW[(k << 7) + cc];
      const float x0 = sX[r0][kc + k];
      const float x1 = sX[r0 + 1][kc + k];
      acc[0][0] = fmaf(x0, w.x, acc[0][0]); acc[0][1] = fmaf(x0, w.y, acc[0][1]);
      acc[0][2] = fmaf(x0, w.z, acc[0][2]); acc[0][3] = fmaf(x0, w.w, acc[0][3]);
      acc[1][0] = fmaf(x1, w.x, acc[1][0]); acc[1][1] = fmaf(x1, w.y, acc[1][1]);
      acc[1][2] = fmaf(x1, w.z, acc[1][2]); acc[1][3] = fmaf(x1, w.w, acc[1][3]);
    }
  }

  const float4 b4 = *(const float4*)(bias + cc);
  float beta = 0.f;
  if (mode == 2) beta = 1.0f / (1.0f + expf(-skip[0]));
#pragma unroll
  for (int i = 0; i < 2; ++i) {
    int row = rowbase + r0 + i;
    float4 t = make_float4(acc[i][0] + b4.x, acc[i][1] + b4.y,
                           acc[i][2] + b4.z, acc[i][3] + b4.w);
    if (mode == 0) {
      t.x = fmaxf(t.x, 0.f); t.y = fmaxf(t.y, 0.f);
      t.z = fmaxf(t.z, 0.f); t.w = fmaxf(t.w, 0.f);
    } else {
      const float4 xo = *(const float4*)(Y + (size_t)row * 128 + cc);
      t.x = beta * t.x + (1.f - beta) * xo.x;
      t.y = beta * t.y + (1.f - beta) * xo.y;
      t.z = beta * t.z + (1.f - beta) * xo.z;
      t.w = beta * t.w + (1.f - beta) * xo.w;
      uint2 pk;
      pk.x = f2bf(t.x) | (f2bf(t.y) << 16);
      pk.y = f2bf(t.z) | (f2bf(t.w) << 16);
      *(uint2*)(cat + (size_t)row * 256 + catoff + cc) = pk;
    }
    *(float4*)(Y + (size_t)row * 128 + cc) = t;
  }
}

// ---------- dual-type fused K/V/Q projection ----------
// q out fp32 (for attn dst reads); ke/ve out bf16 (gather tables)
__launch_bounds__(256, 2)
__global__ void kvq_dual(const float* __restrict__ X1,
                         const float* __restrict__ Wq1, const float* __restrict__ bq1,
                         const float* __restrict__ Wk1, const float* __restrict__ bk1,
                         const float* __restrict__ Wv1, const float* __restrict__ bv1,
                         float* __restrict__ q1o, ushort_t* __restrict__ ke1, ushort_t* __restrict__ ve1,
                         const float* __restrict__ X2,
                         const float* __restrict__ Wq2, const float* __restrict__ bq2,
                         const float* __restrict__ Wk2, const float* __restrict__ bk2,
                         const float* __restrict__ Wv2, const float* __restrict__ bv2,
                         float* __restrict__ q2o, ushort_t* __restrict__ ke2, ushort_t* __restrict__ ve2,
                         int nb1)
{
  __shared__ float sW[64 * 128];
  __shared__ float sX[GEMM_ROWS][132];
  const int bid = blockIdx.x;
  const bool t2 = bid >= nb1;
  const float* X = t2 ? X2 : X1;
  const float* Ws[3] = { t2 ? Wq2 : Wq1, t2 ? Wk2 : Wk1, t2 ? Wv2 : Wv1 };
  const float* bs[3] = { t2 ? bq2 : bq1, t2 ? bk2 : bk1, t2 ? bv2 : bv1 };
  float* qo = t2 ? q2o : q1o;
  ushort_t* keo = t2 ? ke2 : ke1;
  ushort_t* veo = t2 ? ve2 : ve1;
  const int tid = threadIdx.x;
  const int rowbase = (t2 ? bid - nb1 : bid) * GEMM_ROWS;

#pragma unroll
  for (int i = 0; i < 2; ++i) {
    int idx = tid + i * 256;
    int r = idx >> 5, c4 = (idx & 31) << 2;
    float4 v = *(const float4*)(X + (size_t)(rowbase + r) * 128 + c4);
    sX[r][c4 + 0] = v.x; sX[r][c4 + 1] = v.y;
    sX[r][c4 + 2] = v.z; sX[r][c4 + 3] = v.w;
  }

  const int r0 = (tid >> 5) << 1;
  const int cc = (tid & 31) << 2;
  float acc[3][2][4] = {};

  for (int j = 0; j < 3; ++j) {
    const float* W = Ws[j];
    for (int kc = 0; kc < 128; kc += 64) {
      __syncthreads();
#pragma unroll
      for (int i = 0; i < 8; ++i) {
        int idx = tid + i * 256;
        *(float4*)&sW[idx << 2] = *(const float4*)(W + (size_t)kc * 128 + (idx << 2));
      }
      __syncthreads();
#pragma unroll 8
      for (int k = 0; k < 64; ++k) {
        const float4 w = *(const float4*)&sW[(k << 7) + cc];
        const float x0 = sX[r0][kc + k];
        const float x1 = sX[r0 + 1][kc + k];
        acc[j][0][0] = fmaf(x0, w.x, acc[j][0][0]); acc[j][0][1] = fmaf(x0, w.y, acc[j][0][1]);
        acc[j][0][2] = fmaf(x0, w.z, acc[j][0][2]); acc[j][0][3] = fmaf(x0, w.w, acc[j][0][3]);
        acc[j][1][0] = fmaf(x1, w.x, acc[j][1][0]); acc[j][1][1] = fmaf(x1, w.y, acc[j][1][1]);
        acc[j][1][2] = fmaf(x1, w.z, acc[j][1][2]); acc[j][1][3] = fmaf(x1, w.w, acc[j][1][3]);
      }
    }
  }

#pragma unroll
  for (int j = 0; j < 3; ++j) {
    const float4 b4 = *(const float4*)(bs[j] + cc);
#pragma unroll
    for (int i = 0; i < 2; ++i) {
      int row = rowbase + r0 + i;
      float4 t = make_float4(acc[j][i][0] + b4.x, acc[j][i][1] + b4.y,
                             acc[j][i][2] + b4.z, acc[j][i][3] + b4.w);
      if (j == 0) {
        *(float4*)(qo + (size_t)row * 128 + cc) = t;
      } else {
        uint2 pk;
        pk.x = f2bf(t.x) | (f2bf(t.y) << 16);
        pk.y = f2bf(t.z) | (f2bf(t.w) << 16);
        ushort_t* dst = (j == 1) ? keo : veo;
        *(uint2*)(dst + (size_t)row * 128 + cc) = pk;
      }
    }
  }
}

// ---------- fold per-head relation matrices (4 jobs in one launch) ----------
__global__ void fuse_rel4(const float* Wk1, const float* bk1, const float* a12,
                          const float* Wv1, const float* bv1, const float* m12,
                          const float* Wk2, const float* bk2, const float* a21,
                          const float* Wv2, const float* bv2, const float* m21,
                          float* WkF1, float* bkF1, float* WvF1, float* bvF1,
                          float* WkF2, float* bkF2, float* WvF2, float* bvF2)
{
  const float *W, *b, *rel; float *Wf, *bf;
  switch (blockIdx.y) {
    case 0:  W = Wk1; b = bk1; rel = a12; Wf = WkF1; bf = bkF1; break;
    case 1:  W = Wv1; b = bv1; rel = m12; Wf = WvF1; bf = bvF1; break;
    case 2:  W = Wk2; b = bk2; rel = a21; Wf = WkF2; bf = bkF2; break;
    default: W = Wv2; b = bv2; rel = m21; Wf = WvF2; bf = bvF2; break;
  }
  int idx = blockIdx.x * 256 + threadIdx.x;
  if (idx >= 129 * 128) return;
  int row = idx >> 7, col = idx & 127;
  int h = col >> 4, e = col & 15;
  const float* rr = rel + h * 256;
  const float* src = (row < 128) ? (W + (size_t)row * 128 + h * 16) : (b + h * 16);
  float acc = 0.f;
#pragma unroll
  for (int d = 0; d < 16; ++d) acc = fmaf(src[d], rr[d * 16 + e], acc);
  if (row < 128) Wf[(size_t)row * 128 + col] = acc;
  else           bf[col] = acc;
}

// ---------- CSR build (both graphs) ----------
__global__ void csr_hist2(const int* __restrict__ dst12, const int* __restrict__ dst21,
                          int* __restrict__ deg12, int* __restrict__ deg21)
{
  int e = blockIdx.x * 256 + threadIdx.x;
  if (e < NE12) atomicAdd(&deg12[dst12[e]], 1);
  if (e < NE21) atomicAdd(&deg21[dst21[e]], 1);
}

__global__ void csr_scan2(const int* __restrict__ degA, int* __restrict__ rowptrA,
                          int* __restrict__ cursorA, int NA, int EA,
                          const int* __restrict__ degB, int* __restrict__ rowptrB,
                          int* __restrict__ cursorB, int NB, int EB)
{
  const int* deg = blockIdx.x ? degB : degA;
  int* rowptr = blockIdx.x ? rowptrB : rowptrA;
  int* cursor = blockIdx.x ? cursorB : cursorA;
  const int N = blockIdx.x ? NB : NA;
  const int E = blockIdx.x ? EB : EA;
  __shared__ int part[256];
  const int t = threadIdx.x;
  const int chunk = (N + 255) / 256;
  const int b = t * chunk;
  const int e = (b + chunk < N) ? b + chunk : N;
  int s = 0;
  for (int i = b; i < e; ++i) s += deg[i];
  part[t] = s;
  __syncthreads();
  if (t == 0) {
    int run = 0;
    for (int i = 0; i < 256; ++i) { int v = part[i]; part[i] = run; run += v; }
  }
  __syncthreads();
  int run = part[t];
  for (int i = b; i < e; ++i) { rowptr[i] = run; cursor[i] = run; run += deg[i]; }
  if (t == 0) rowptr[N] = E;
}

__global__ void csr_scatter2(const int* __restrict__ src12, const int* __restrict__ dst12,
                             int* __restrict__ cur12, int* __restrict__ csr12,
                             const int* __restrict__ src21, const int* __restrict__ dst21,
                             int* __restrict__ cur21, int* __restrict__ csr21)
{
  int e = blockIdx.x * 256 + threadIdx.x;
  if (e < NE12) { int p = atomicAdd(&cur12[dst12[e]], 1); csr12[p] = src12[e]; }
  if (e < NE21) { int p = atomicAdd(&cur21[dst21[e]], 1); csr21[p] = src21[e]; }
}

// ---------- fused gather attention, both directions, bf16 tables ----------
// one wave per dst node; 2 channels per lane; next-edge prefetch
__launch_bounds__(256)
__global__ void attn_gather2(const int* __restrict__ rowptr12, const int* __restrict__ csr12,
                             const float* __restrict__ q2, const ushort_t* __restrict__ ke1,
                             const ushort_t* __restrict__ ve1, const float* __restrict__ pr12,
                             const int* __restrict__ rowptr21, const int* __restrict__ csr21,
                             const float* __restrict__ q1, const ushort_t* __restrict__ ke2,
                             const ushort_t* __restrict__ ve2, const float* __restrict__ pr21,
                             float* __restrict__ agg2, float* __restrict__ agg1)
{
  const int wid = (blockIdx.x * 256 + threadIdx.x) >> 6;
  const int lane = threadIdx.x & 63;
  const bool dirB = wid >= PN2;
  const int d = dirB ? wid - PN2 : wid;
  const int* rowptr = dirB ? rowptr21 : rowptr12;
  const int* csr    = dirB ? csr21 : csr12;
  const float* q    = dirB ? q1 : q2;
  const ushort_t* ke = dirB ? ke2 : ke1;
  const ushort_t* ve = dirB ? ve2 : ve1;
  const float* prel = dirB ? pr21 : pr12;
  float* agg = dirB ? agg1 : agg2;

  const int h = lane >> 3;
  const float2 qv = *(const float2*)(q + (size_t)d * 128 + 2 * lane);
  const float pr = prel[h] * 0.25f;     // p_rel / sqrt(16)
  const int beg = rowptr[d], end = rowptr[d + 1];

  float m = -1e30f, ssum = 0.f, a0 = 0.f, a1 = 0.f;
  unsigned kn = 0, vn = 0;
  if (beg < end) {
    int s0 = csr[beg];
    kn = *(const unsigned*)(ke + (size_t)s0 * 128 + 2 * lane);
    vn = *(const unsigned*)(ve + (size_t)s0 * 128 + 2 * lane);
  }
  for (int i = beg; i < end; ++i) {
    const unsigned kc = kn, vc = vn;
    if (i + 1 < end) {
      int sn = csr[i + 1];
      kn = *(const unsigned*)(ke + (size_t)sn * 128 + 2 * lane);
      vn = *(const unsigned*)(ve + (size_t)sn * 128 + 2 * lane);
    }
    const float k0 = bf2f(kc & 0xffffu), k1 = bf2f(kc >> 16);
    float p = fmaf(qv.x, k0, qv.y * k1);
    p += __shfl_xor(p, 1); p += __shfl_xor(p, 2); p += __shfl_xor(p, 4);
    const float a = p * pr;
    const float nm = fmaxf(m, a);
    const float f  = __expf(m - nm);
    const float ex = __expf(a - nm);
    const float v0 = bf2f(vc & 0xffffu), v1 = bf2f(vc >> 16);
    ssum = fmaf(ssum, f, ex);
    a0 = fmaf(a0, f, ex * v0);
    a1 = fmaf(a1, f, ex * v1);
    m = nm;
  }
  float o0 = a0 / (ssum + 1e-16f);
  float o1 = a1 / (ssum + 1e-16f);
  o0 = 0.5f * o0 * (1.f + erff(o0 * 0.70710678118654752f));
  o1 = 0.5f * o1 * (1.f + erff(o1 * 0.70710678118654752f));
  float2 out; out.x = o0; out.y = o1;
  *(float2*)(agg + (size_t)d * 128 + 2 * lane) = out;
}

// ---------- readout on bf16 Em/Ed: 16 lanes per edge ----------
__launch_bounds__(256)
__global__ void edge_dot_bf(const int* __restrict__ mi, const int* __restrict__ di,
                            const ushort_t* __restrict__ Em, const ushort_t* __restrict__ Ed,
                            float* __restrict__ y, int E)
{
  int t = blockIdx.x * 256 + threadIdx.x;
  int e = t >> 4;
  int l = t & 15;
  if (e >= E) return;
  int m = mi[e], d = di[e];
  const uint4* A = (const uint4*)(Em + (size_t)m * 256);
  const uint4* B = (const uint4*)(Ed + (size_t)d * 256);
  float acc = 0.f;
#pragma unroll
  for (int i = 0; i < 2; ++i) {
    uint4 a = A[l + 16 * i];
    uint4 b = B[l + 16 * i];
    acc = fmaf(bf2f(a.x & 0xffffu), bf2f(b.x & 0xffffu), acc);
    acc = fmaf(bf2f(a.x >> 16),     bf2f(b.x >> 16),     acc);
    acc = fmaf(bf2f(a.y & 0xffffu), bf2f(b.y & 0xffffu), acc);
    acc = fmaf(bf2f(a.y >> 16),     bf2f(b.y >> 16),     acc);
    acc = fmaf(bf2f(a.z & 0xffffu), bf2f(b.z & 0xffffu), acc);
    acc = fmaf(bf2f(a.z >> 16),     bf2f(b.z >> 16),     acc);
    acc = fmaf(bf2f(a.w & 0xffffu), bf2f(b.w & 0xffffu), acc);
    acc = fmaf(bf2f(a.w >> 16),     bf2f(b.w >> 16),     acc);
  }
#pragma unroll
  for (int off = 8; off >= 1; off >>= 1) acc += __shfl_xor(acc, off);
  if (l == 0) y[e] = acc;
}

// ---------- launch ----------
extern "C" void kernel_launch(void* const* d_in, const int* in_sizes, int n_in,
                              void* d_out, int out_size, void* d_ws, size_t ws_size,
                              hipStream_t stream)
{
  const float* x_n1  = (const float*)d_in[0];
  const float* x_n2  = (const float*)d_in[1];
  const float* W_in1 = (const float*)d_in[2];
  const float* b_in1 = (const float*)d_in[3];
  const float* W_in2 = (const float*)d_in[4];
  const float* b_in2 = (const float*)d_in[5];
  const float* Wk_n1 = (const float*)d_in[6];
  const float* bk_n1 = (const float*)d_in[7];
  const float* Wq_n1 = (const float*)d_in[8];
  const float* bq_n1 = (const float*)d_in[9];
  const float* Wv_n1 = (const float*)d_in[10];
  const float* bv_n1 = (const float*)d_in[11];
  const float* Wa_n1 = (const float*)d_in[12];
  const float* ba_n1 = (const float*)d_in[13];
  const float* skip_n1 = (const float*)d_in[14];
  const float* Wk_n2 = (const float*)d_in[15];
  const float* bk_n2 = (const float*)d_in[16];
  const float* Wq_n2 = (const float*)d_in[17];
  const float* bq_n2 = (const float*)d_in[18];
  const float* Wv_n2 = (const float*)d_in[19];
  const float* bv_n2 = (const float*)d_in[20];
  const float* Wa_n2 = (const float*)d_in[21];
  const float* ba_n2 = (const float*)d_in[22];
  const float* skip_n2 = (const float*)d_in[23];
  const float* a_rel_12 = (const float*)d_in[24];
  const float* m_rel_12 = (const float*)d_in[25];
  const float* p_rel_12 = (const float*)d_in[26];
  const float* a_rel_21 = (const float*)d_in[27];
  const float* m_rel_21 = (const float*)d_in[28];
  const float* p_rel_21 = (const float*)d_in[29];
  const int*   ei_12 = (const int*)d_in[30];
  const int*   ei_21 = (const int*)d_in[31];
  const int*   edge_index = (const int*)d_in[32];
  float* y = (float*)d_out;

  // ---- workspace carve-up (float units) ----
  const size_t NF = (size_t)PN1 * 128;       // 1,280,000
  float* ws = (float*)d_ws;
  float* x1   = ws + 0 * NF;
  float* x2   = ws + 1 * NF;
  float* q1   = ws + 2 * NF;
  float* q2   = ws + 3 * NF;
  float* agg1 = ws + 4 * NF;
  float* agg2 = ws + 5 * NF;
  ushort_t* ke1 = (ushort_t*)(ws + 6 * NF);              // [N,128] bf16
  ushort_t* ve1 = (ushort_t*)(ws + 6 * NF +  640000);
  ushort_t* ke2 = (ushort_t*)(ws + 6 * NF + 1280000);
  ushort_t* ve2 = (ushort_t*)(ws + 6 * NF + 1920000);
  ushort_t* Em  = (ushort_t*)(ws + 6 * NF + 2560000);    // [N1,256] bf16
  ushort_t* Ed  = (ushort_t*)(ws + 6 * NF + 3840000);
  float* WkF1 = ws + 6 * NF + 5120000;  float* bkF1 = WkF1 + 16384;
  float* WvF1 = WkF1 + 16512;           float* bvF1 = WvF1 + 16384;
  float* WkF2 = WvF1 + 16512;           float* bkF2 = WkF2 + 16384;
  float* WvF2 = WkF2 + 16512;           float* bvF2 = WvF2 + 16384;
  int* ip = (int*)(WvF2 + 16512);
  int* rowptr12 = ip;                   // 10016 each
  int* rowptr21 = ip + 10016;
  int* cur12    = ip + 20032;
  int* cur21    = ip + 30048;
  int* deg12    = ip + 40064;           // deg12/deg21 adjacent: single memset
  int* deg21    = ip + 50080;
  int* csr12    = ip + 60096;
  int* csr21    = ip + 60096 + NE12;

  const int NB = PN1 / GEMM_ROWS;            // 625 blocks per type
  const int EB = (NE12 + 255) / 256;         // 1250

  // ---- CSR build (graph constant across layers) ----
  hipMemsetAsync(deg12, 0, 2 * 10016 * sizeof(int), stream);
  csr_hist2<<<EB, 256, 0, stream>>>(ei_12 + NE12, ei_21 + NE21, deg12, deg21);
  csr_scan2<<<2, 256, 0, stream>>>(deg12, rowptr12, cur12, PN2, NE12,
                                   deg21, rowptr21, cur21, PN1, NE21);
  csr_scatter2<<<EB, 256, 0, stream>>>(ei_12, ei_12 + NE12, cur12, csr12,
                                       ei_21, ei_21 + NE21, cur21, csr21);

  // ---- input projections + relu (both types, one launch) ----
  gemm_dual<<<2 * NB, 256, 0, stream>>>(x_n1, W_in1, b_in1, x1,
                                        x_n2, W_in2, b_in2, x2,
                                        NB, 0, nullptr, nullptr, nullptr, nullptr, 0);

  for (int l = 0; l < NLAY; ++l) {
    const size_t wo = (size_t)l * 16384;
    const int bo = l * 128;

    fuse_rel4<<<dim3(65, 4), 256, 0, stream>>>(
        Wk_n1 + wo, bk_n1 + bo, a_rel_12 + (size_t)l * 2048,
        Wv_n1 + wo, bv_n1 + bo, m_rel_12 + (size_t)l * 2048,
        Wk_n2 + wo, bk_n2 + bo, a_rel_21 + (size_t)l * 2048,
        Wv_n2 + wo, bv_n2 + bo, m_rel_21 + (size_t)l * 2048,
        WkF1, bkF1, WvF1, bvF1, WkF2, bkF2, WvF2, bvF2);

    kvq_dual<<<2 * NB, 256, 0, stream>>>(
        x1, Wq_n1 + wo, bq_n1 + bo, WkF1, bkF1, WvF1, bvF1, q1, ke1, ve1,
        x2, Wq_n2 + wo, bq_n2 + bo, WkF2, bkF2, WvF2, bvF2, q2, ke2, ve2, NB);

    attn_gather2<<<(2 * PN1) / 4, 256, 0, stream>>>(
        rowptr12, csr12, q2, ke1, ve1, p_rel_12 + l * NH,
        rowptr21, csr21, q1, ke2, ve2, p_rel_21 + l * NH,
        agg2, agg1);

    gemm_dual<<<2 * NB, 256, 0, stream>>>(agg1, Wa_n1 + wo, ba_n1 + bo, x1,
                                          agg2, Wa_n2 + wo, ba_n2 + bo, x2,
                                          NB, 2, skip_n1 + l, skip_n2 + l, Em, Ed, bo);
  }

  // ---- readout ----
  const int DOT_B = (NEF * 16 + 255) / 256;
  edge_dot_bf<<<DOT_B, 256, 0, stream>>>(edge_index, edge_index + NEF, Em, Ed, y, NEF);
}

// Round 4
// 528.929 us; speedup vs baseline: 18.7074x; 1.0838x over previous
//
#include <hip/hip_runtime.h>
#include <cstdint>
#include <cstddef>

typedef unsigned short ushort_t;

// Problem constants
#define PN1   10000
#define PN2   10000
#define NH    8
#define NLAY  2
#define NE12  320000
#define NE21  320000
#define NEF   500000

// ---------- bf16 helpers (RNE) ----------
__device__ __forceinline__ unsigned f2bf(float f) {
  union { float f; unsigned u; } v; v.f = f;
  return (v.u + 0x7FFFu + ((v.u >> 16) & 1u)) >> 16;
}
__device__ __forceinline__ float bf2f(unsigned s) {
  union { float f; unsigned u; } v; v.u = s << 16; return v.f;
}

// ---------- dual-type GEMM: Y[N,128] = act(X @ W + b) ----------
// mode 0: relu   mode 2: skip-blend + bf16 concat write
#define GEMM_ROWS 16
__launch_bounds__(256, 2)
__global__ void gemm_dual(const float* __restrict__ X1, const float* __restrict__ W1,
                          const float* __restrict__ b1, float* __restrict__ Y1,
                          const float* __restrict__ X2, const float* __restrict__ W2,
                          const float* __restrict__ b2, float* __restrict__ Y2,
                          int nb1, int mode,
                          const float* __restrict__ skip1, const float* __restrict__ skip2,
                          ushort_t* __restrict__ cat1, ushort_t* __restrict__ cat2, int catoff)
{
  __shared__ float sW[64 * 128];
  __shared__ float sX[GEMM_ROWS][132];
  const int bid = blockIdx.x;
  const bool t2 = bid >= nb1;
  const float* X = t2 ? X2 : X1;  const float* W = t2 ? W2 : W1;
  const float* bias = t2 ? b2 : b1;  float* Y = t2 ? Y2 : Y1;
  const float* skip = t2 ? skip2 : skip1;
  ushort_t* cat = t2 ? cat2 : cat1;
  const int tid = threadIdx.x;
  const int rowbase = (t2 ? bid - nb1 : bid) * GEMM_ROWS;

#pragma unroll
  for (int i = 0; i < 2; ++i) {
    int idx = tid + i * 256;
    int r = idx >> 5, c4 = (idx & 31) << 2;
    float4 v = *(const float4*)(X + (size_t)(rowbase + r) * 128 + c4);
    sX[r][c4 + 0] = v.x; sX[r][c4 + 1] = v.y;
    sX[r][c4 + 2] = v.z; sX[r][c4 + 3] = v.w;
  }

  const int r0 = (tid >> 5) << 1;
  const int cc = (tid & 31) << 2;
  float acc[2][4] = {{0.f,0.f,0.f,0.f},{0.f,0.f,0.f,0.f}};

  for (int kc = 0; kc < 128; kc += 64) {
    __syncthreads();
#pragma unroll
    for (int i = 0; i < 8; ++i) {
      int idx = tid + i * 256;
      *(float4*)&sW[idx << 2] = *(const float4*)(W + (size_t)kc * 128 + (idx << 2));
    }
    __syncthreads();
#pragma unroll 8
    for (int k = 0; k < 64; ++k) {
      const float4 w = *(const float4*)&sW[(k << 7) + cc];
      const float x0 = sX[r0][kc + k];
      const float x1 = sX[r0 + 1][kc + k];
      acc[0][0] = fmaf(x0, w.x, acc[0][0]); acc[0][1] = fmaf(x0, w.y, acc[0][1]);
      acc[0][2] = fmaf(x0, w.z, acc[0][2]); acc[0][3] = fmaf(x0, w.w, acc[0][3]);
      acc[1][0] = fmaf(x1, w.x, acc[1][0]); acc[1][1] = fmaf(x1, w.y, acc[1][1]);
      acc[1][2] = fmaf(x1, w.z, acc[1][2]); acc[1][3] = fmaf(x1, w.w, acc[1][3]);
    }
  }

  const float4 b4 = *(const float4*)(bias + cc);
  float beta = 0.f;
  if (mode == 2) beta = 1.0f / (1.0f + expf(-skip[0]));
#pragma unroll
  for (int i = 0; i < 2; ++i) {
    int row = rowbase + r0 + i;
    float4 t = make_float4(acc[i][0] + b4.x, acc[i][1] + b4.y,
                           acc[i][2] + b4.z, acc[i][3] + b4.w);
    if (mode == 0) {
      t.x = fmaxf(t.x, 0.f); t.y = fmaxf(t.y, 0.f);
      t.z = fmaxf(t.z, 0.f); t.w = fmaxf(t.w, 0.f);
    } else {
      const float4 xo = *(const float4*)(Y + (size_t)row * 128 + cc);
      t.x = beta * t.x + (1.f - beta) * xo.x;
      t.y = beta * t.y + (1.f - beta) * xo.y;
      t.z = beta * t.z + (1.f - beta) * xo.z;
      t.w = beta * t.w + (1.f - beta) * xo.w;
      uint2 pk;
      pk.x = f2bf(t.x) | (f2bf(t.y) << 16);
      pk.y = f2bf(t.z) | (f2bf(t.w) << 16);
      *(uint2*)(cat + (size_t)row * 256 + catoff + cc) = pk;
    }
    *(float4*)(Y + (size_t)row * 128 + cc) = t;
  }
}

// ---------- dual-type fused K/V/Q projection ----------
__launch_bounds__(256, 2)
__global__ void kvq_dual(const float* __restrict__ X1,
                         const float* __restrict__ Wq1, const float* __restrict__ bq1,
                         const float* __restrict__ Wk1, const float* __restrict__ bk1,
                         const float* __restrict__ Wv1, const float* __restrict__ bv1,
                         float* __restrict__ q1o, ushort_t* __restrict__ ke1, ushort_t* __restrict__ ve1,
                         const float* __restrict__ X2,
                         const float* __restrict__ Wq2, const float* __restrict__ bq2,
                         const float* __restrict__ Wk2, const float* __restrict__ bk2,
                         const float* __restrict__ Wv2, const float* __restrict__ bv2,
                         float* __restrict__ q2o, ushort_t* __restrict__ ke2, ushort_t* __restrict__ ve2,
                         int nb1)
{
  __shared__ float sW[64 * 128];
  __shared__ float sX[GEMM_ROWS][132];
  const int bid = blockIdx.x;
  const bool t2 = bid >= nb1;
  const float* X = t2 ? X2 : X1;
  const float* Ws[3] = { t2 ? Wq2 : Wq1, t2 ? Wk2 : Wk1, t2 ? Wv2 : Wv1 };
  const float* bs[3] = { t2 ? bq2 : bq1, t2 ? bk2 : bk1, t2 ? bv2 : bv1 };
  float* qo = t2 ? q2o : q1o;
  ushort_t* keo = t2 ? ke2 : ke1;
  ushort_t* veo = t2 ? ve2 : ve1;
  const int tid = threadIdx.x;
  const int rowbase = (t2 ? bid - nb1 : bid) * GEMM_ROWS;

#pragma unroll
  for (int i = 0; i < 2; ++i) {
    int idx = tid + i * 256;
    int r = idx >> 5, c4 = (idx & 31) << 2;
    float4 v = *(const float4*)(X + (size_t)(rowbase + r) * 128 + c4);
    sX[r][c4 + 0] = v.x; sX[r][c4 + 1] = v.y;
    sX[r][c4 + 2] = v.z; sX[r][c4 + 3] = v.w;
  }

  const int r0 = (tid >> 5) << 1;
  const int cc = (tid & 31) << 2;
  float acc[3][2][4] = {};

  for (int j = 0; j < 3; ++j) {
    const float* W = Ws[j];
    for (int kc = 0; kc < 128; kc += 64) {
      __syncthreads();
#pragma unroll
      for (int i = 0; i < 8; ++i) {
        int idx = tid + i * 256;
        *(float4*)&sW[idx << 2] = *(const float4*)(W + (size_t)kc * 128 + (idx << 2));
      }
      __syncthreads();
#pragma unroll 8
      for (int k = 0; k < 64; ++k) {
        const float4 w = *(const float4*)&sW[(k << 7) + cc];
        const float x0 = sX[r0][kc + k];
        const float x1 = sX[r0 + 1][kc + k];
        acc[j][0][0] = fmaf(x0, w.x, acc[j][0][0]); acc[j][0][1] = fmaf(x0, w.y, acc[j][0][1]);
        acc[j][0][2] = fmaf(x0, w.z, acc[j][0][2]); acc[j][0][3] = fmaf(x0, w.w, acc[j][0][3]);
        acc[j][1][0] = fmaf(x1, w.x, acc[j][1][0]); acc[j][1][1] = fmaf(x1, w.y, acc[j][1][1]);
        acc[j][1][2] = fmaf(x1, w.z, acc[j][1][2]); acc[j][1][3] = fmaf(x1, w.w, acc[j][1][3]);
      }
    }
  }

#pragma unroll
  for (int j = 0; j < 3; ++j) {
    const float4 b4 = *(const float4*)(bs[j] + cc);
#pragma unroll
    for (int i = 0; i < 2; ++i) {
      int row = rowbase + r0 + i;
      float4 t = make_float4(acc[j][i][0] + b4.x, acc[j][i][1] + b4.y,
                             acc[j][i][2] + b4.z, acc[j][i][3] + b4.w);
      if (j == 0) {
        *(float4*)(qo + (size_t)row * 128 + cc) = t;
      } else {
        uint2 pk;
        pk.x = f2bf(t.x) | (f2bf(t.y) << 16);
        pk.y = f2bf(t.z) | (f2bf(t.w) << 16);
        ushort_t* dst = (j == 1) ? keo : veo;
        *(uint2*)(dst + (size_t)row * 128 + cc) = pk;
      }
    }
  }
}

// ---------- fold per-head relation matrices (4 jobs in one launch) ----------
__global__ void fuse_rel4(const float* Wk1, const float* bk1, const float* a12,
                          const float* Wv1, const float* bv1, const float* m12,
                          const float* Wk2, const float* bk2, const float* a21,
                          const float* Wv2, const float* bv2, const float* m21,
                          float* WkF1, float* bkF1, float* WvF1, float* bvF1,
                          float* WkF2, float* bkF2, float* WvF2, float* bvF2)
{
  const float *W, *b, *rel; float *Wf, *bf;
  switch (blockIdx.y) {
    case 0:  W = Wk1; b = bk1; rel = a12; Wf = WkF1; bf = bkF1; break;
    case 1:  W = Wv1; b = bv1; rel = m12; Wf = WvF1; bf = bvF1; break;
    case 2:  W = Wk2; b = bk2; rel = a21; Wf = WkF2; bf = bkF2; break;
    default: W = Wv2; b = bv2; rel = m21; Wf = WvF2; bf = bvF2; break;
  }
  int idx = blockIdx.x * 256 + threadIdx.x;
  if (idx >= 129 * 128) return;
  int row = idx >> 7, col = idx & 127;
  int h = col >> 4, e = col & 15;
  const float* rr = rel + h * 256;
  const float* src = (row < 128) ? (W + (size_t)row * 128 + h * 16) : (b + h * 16);
  float acc = 0.f;
#pragma unroll
  for (int d = 0; d < 16; ++d) acc = fmaf(src[d], rr[d * 16 + e], acc);
  if (row < 128) Wf[(size_t)row * 128 + col] = acc;
  else           bf[col] = acc;
}

// ---------- CSR build (both graphs) ----------
__global__ void csr_hist2(const int* __restrict__ dst12, const int* __restrict__ dst21,
                          int* __restrict__ deg12, int* __restrict__ deg21)
{
  int e = blockIdx.x * 256 + threadIdx.x;
  if (e < NE12) atomicAdd(&deg12[dst12[e]], 1);
  if (e < NE21) atomicAdd(&deg21[dst21[e]], 1);
}

__global__ void csr_scan2(const int* __restrict__ degA, int* __restrict__ rowptrA,
                          int* __restrict__ cursorA, int NA, int EA,
                          const int* __restrict__ degB, int* __restrict__ rowptrB,
                          int* __restrict__ cursorB, int NB, int EB)
{
  const int* deg = blockIdx.x ? degB : degA;
  int* rowptr = blockIdx.x ? rowptrB : rowptrA;
  int* cursor = blockIdx.x ? cursorB : cursorA;
  const int N = blockIdx.x ? NB : NA;
  const int E = blockIdx.x ? EB : EA;
  __shared__ int part[256];
  const int t = threadIdx.x;
  const int chunk = (N + 255) / 256;
  const int b = t * chunk;
  const int e = (b + chunk < N) ? b + chunk : N;
  int s = 0;
  for (int i = b; i < e; ++i) s += deg[i];
  part[t] = s;
  __syncthreads();
  if (t == 0) {
    int run = 0;
    for (int i = 0; i < 256; ++i) { int v = part[i]; part[i] = run; run += v; }
  }
  __syncthreads();
  int run = part[t];
  for (int i = b; i < e; ++i) { rowptr[i] = run; cursor[i] = run; run += deg[i]; }
  if (t == 0) rowptr[N] = E;
}

__global__ void csr_scatter2(const int* __restrict__ src12, const int* __restrict__ dst12,
                             int* __restrict__ cur12, int* __restrict__ csr12,
                             const int* __restrict__ src21, const int* __restrict__ dst21,
                             int* __restrict__ cur21, int* __restrict__ csr21)
{
  int e = blockIdx.x * 256 + threadIdx.x;
  if (e < NE12) { int p = atomicAdd(&cur12[dst12[e]], 1); csr12[p] = src12[e]; }
  if (e < NE21) { int p = atomicAdd(&cur21[dst21[e]], 1); csr21[p] = src21[e]; }
}

// ---------- fused gather attention, both directions, bf16 tables ----------
// one wave per dst node; 2 channels per lane.
// No max-subtraction: |alpha| << 1 here, exp cannot overflow, and dropping the
// online-softmax rescale removes the ~20-cycle loop-carried chain -> iterations
// are independent (accumulator fma only) and software-pipeline freely.
__launch_bounds__(256)
__global__ void attn_gather2(const int* __restrict__ rowptr12, const int* __restrict__ csr12,
                             const float* __restrict__ q2, const ushort_t* __restrict__ ke1,
                             const ushort_t* __restrict__ ve1, const float* __restrict__ pr12,
                             const int* __restrict__ rowptr21, const int* __restrict__ csr21,
                             const float* __restrict__ q1, const ushort_t* __restrict__ ke2,
                             const ushort_t* __restrict__ ve2, const float* __restrict__ pr21,
                             float* __restrict__ agg2, float* __restrict__ agg1)
{
  const int wid = (blockIdx.x * 256 + threadIdx.x) >> 6;
  const int lane = threadIdx.x & 63;
  const bool dirB = wid >= PN2;
  const int d = dirB ? wid - PN2 : wid;
  const int* rowptr = dirB ? rowptr21 : rowptr12;
  const int* csr    = dirB ? csr21 : csr12;
  const float* q    = dirB ? q1 : q2;
  const ushort_t* ke = dirB ? ke2 : ke1;
  const ushort_t* ve = dirB ? ve2 : ve1;
  const float* prel = dirB ? pr21 : pr12;
  float* agg = dirB ? agg1 : agg2;

  const int h = lane >> 3;
  const float2 qv = *(const float2*)(q + (size_t)d * 128 + 2 * lane);
  const float pr = prel[h] * 0.25f;     // p_rel / sqrt(16)
  const int beg = rowptr[d], end = rowptr[d + 1];
  const int co = 2 * lane;

  float ssum = 0.f, a0 = 0.f, a1 = 0.f;

  // 2-wide software pipeline: pair (ka,va),(kb,vb) in flight, next pair prefetched
  unsigned ka = 0, va = 0, kb = 0, vb = 0;
  {
    if (beg < end) {
      int s = csr[beg];
      ka = *(const unsigned*)(ke + (size_t)s * 128 + co);
      va = *(const unsigned*)(ve + (size_t)s * 128 + co);
    }
    if (beg + 1 < end) {
      int s = csr[beg + 1];
      kb = *(const unsigned*)(ke + (size_t)s * 128 + co);
      vb = *(const unsigned*)(ve + (size_t)s * 128 + co);
    }
  }
  for (int i = beg; i < end; i += 2) {
    const unsigned kca = ka, vca = va, kcb = kb, vcb = vb;
    const bool has2 = (i + 1 < end);
    if (i + 2 < end) {
      int s = csr[i + 2];
      ka = *(const unsigned*)(ke + (size_t)s * 128 + co);
      va = *(const unsigned*)(ve + (size_t)s * 128 + co);
    }
    if (i + 3 < end) {
      int s = csr[i + 3];
      kb = *(const unsigned*)(ke + (size_t)s * 128 + co);
      vb = *(const unsigned*)(ve + (size_t)s * 128 + co);
    }
    // edge A and B: independent dot + reduce + exp
    float pA = fmaf(qv.x, bf2f(kca & 0xffffu), qv.y * bf2f(kca >> 16));
    float pB = fmaf(qv.x, bf2f(kcb & 0xffffu), qv.y * bf2f(kcb >> 16));
    pA += __shfl_xor(pA, 1); pB += __shfl_xor(pB, 1);
    pA += __shfl_xor(pA, 2); pB += __shfl_xor(pB, 2);
    pA += __shfl_xor(pA, 4); pB += __shfl_xor(pB, 4);
    const float exA = __expf(pA * pr);
    const float exB = has2 ? __expf(pB * pr) : 0.f;
    ssum += exA + exB;
    a0 = fmaf(exA, bf2f(vca & 0xffffu), a0);
    a1 = fmaf(exA, bf2f(vca >> 16),     a1);
    a0 = fmaf(exB, bf2f(vcb & 0xffffu), a0);
    a1 = fmaf(exB, bf2f(vcb >> 16),     a1);
  }

  float o0 = a0 / (ssum + 1e-16f);
  float o1 = a1 / (ssum + 1e-16f);
  o0 = 0.5f * o0 * (1.f + erff(o0 * 0.70710678118654752f));
  o1 = 0.5f * o1 * (1.f + erff(o1 * 0.70710678118654752f));
  float2 out; out.x = o0; out.y = o1;
  *(float2*)(agg + (size_t)d * 128 + co) = out;
}

// ---------- readout on bf16 Em/Ed: 16 lanes per edge ----------
__launch_bounds__(256)
__global__ void edge_dot_bf(const int* __restrict__ mi, const int* __restrict__ di,
                            const ushort_t* __restrict__ Em, const ushort_t* __restrict__ Ed,
                            float* __restrict__ y, int E)
{
  int t = blockIdx.x * 256 + threadIdx.x;
  int e = t >> 4;
  int l = t & 15;
  if (e >= E) return;
  int m = mi[e], d = di[e];
  const uint4* A = (const uint4*)(Em + (size_t)m * 256);
  const uint4* B = (const uint4*)(Ed + (size_t)d * 256);
  float acc = 0.f;
#pragma unroll
  for (int i = 0; i < 2; ++i) {
    uint4 a = A[l + 16 * i];
    uint4 b = B[l + 16 * i];
    acc = fmaf(bf2f(a.x & 0xffffu), bf2f(b.x & 0xffffu), acc);
    acc = fmaf(bf2f(a.x >> 16),     bf2f(b.x >> 16),     acc);
    acc = fmaf(bf2f(a.y & 0xffffu), bf2f(b.y & 0xffffu), acc);
    acc = fmaf(bf2f(a.y >> 16),     bf2f(b.y >> 16),     acc);
    acc = fmaf(bf2f(a.z & 0xffffu), bf2f(b.z & 0xffffu), acc);
    acc = fmaf(bf2f(a.z >> 16),     bf2f(b.z >> 16),     acc);
    acc = fmaf(bf2f(a.w & 0xffffu), bf2f(b.w & 0xffffu), acc);
    acc = fmaf(bf2f(a.w >> 16),     bf2f(b.w >> 16),     acc);
  }
#pragma unroll
  for (int off = 8; off >= 1; off >>= 1) acc += __shfl_xor(acc, off);
  if (l == 0) y[e] = acc;
}

// ---------- launch ----------
extern "C" void kernel_launch(void* const* d_in, const int* in_sizes, int n_in,
                              void* d_out, int out_size, void* d_ws, size_t ws_size,
                              hipStream_t stream)
{
  const float* x_n1  = (const float*)d_in[0];
  const float* x_n2  = (const float*)d_in[1];
  const float* W_in1 = (const float*)d_in[2];
  const float* b_in1 = (const float*)d_in[3];
  const float* W_in2 = (const float*)d_in[4];
  const float* b_in2 = (const float*)d_in[5];
  const float* Wk_n1 = (const float*)d_in[6];
  const float* bk_n1 = (const float*)d_in[7];
  const float* Wq_n1 = (const float*)d_in[8];
  const float* bq_n1 = (const float*)d_in[9];
  const float* Wv_n1 = (const float*)d_in[10];
  const float* bv_n1 = (const float*)d_in[11];
  const float* Wa_n1 = (const float*)d_in[12];
  const float* ba_n1 = (const float*)d_in[13];
  const float* skip_n1 = (const float*)d_in[14];
  const float* Wk_n2 = (const float*)d_in[15];
  const float* bk_n2 = (const float*)d_in[16];
  const float* Wq_n2 = (const float*)d_in[17];
  const float* bq_n2 = (const float*)d_in[18];
  const float* Wv_n2 = (const float*)d_in[19];
  const float* bv_n2 = (const float*)d_in[20];
  const float* Wa_n2 = (const float*)d_in[21];
  const float* ba_n2 = (const float*)d_in[22];
  const float* skip_n2 = (const float*)d_in[23];
  const float* a_rel_12 = (const float*)d_in[24];
  const float* m_rel_12 = (const float*)d_in[25];
  const float* p_rel_12 = (const float*)d_in[26];
  const float* a_rel_21 = (const float*)d_in[27];
  const float* m_rel_21 = (const float*)d_in[28];
  const float* p_rel_21 = (const float*)d_in[29];
  const int*   ei_12 = (const int*)d_in[30];
  const int*   ei_21 = (const int*)d_in[31];
  const int*   edge_index = (const int*)d_in[32];
  float* y = (float*)d_out;

  // ---- workspace carve-up (float units) ----
  const size_t NF = (size_t)PN1 * 128;       // 1,280,000
  float* ws = (float*)d_ws;
  float* x1   = ws + 0 * NF;
  float* x2   = ws + 1 * NF;
  float* q1   = ws + 2 * NF;
  float* q2   = ws + 3 * NF;
  float* agg1 = ws + 4 * NF;
  float* agg2 = ws + 5 * NF;
  ushort_t* ke1 = (ushort_t*)(ws + 6 * NF);              // [N,128] bf16
  ushort_t* ve1 = (ushort_t*)(ws + 6 * NF +  640000);
  ushort_t* ke2 = (ushort_t*)(ws + 6 * NF + 1280000);
  ushort_t* ve2 = (ushort_t*)(ws + 6 * NF + 1920000);
  ushort_t* Em  = (ushort_t*)(ws + 6 * NF + 2560000);    // [N1,256] bf16
  ushort_t* Ed  = (ushort_t*)(ws + 6 * NF + 3840000);
  float* WkF1 = ws + 6 * NF + 5120000;  float* bkF1 = WkF1 + 16384;
  float* WvF1 = WkF1 + 16512;           float* bvF1 = WvF1 + 16384;
  float* WkF2 = WvF1 + 16512;           float* bkF2 = WkF2 + 16384;
  float* WvF2 = WkF2 + 16512;           float* bvF2 = WvF2 + 16384;
  int* ip = (int*)(WvF2 + 16512);
  int* rowptr12 = ip;                   // 10016 each
  int* rowptr21 = ip + 10016;
  int* cur12    = ip + 20032;
  int* cur21    = ip + 30048;
  int* deg12    = ip + 40064;
  int* deg21    = ip + 50080;
  int* csr12    = ip + 60096;
  int* csr21    = ip + 60096 + NE12;

  const int NB = PN1 / GEMM_ROWS;            // 625 blocks per type
  const int EB = (NE12 + 255) / 256;         // 1250

  // ---- CSR build (graph constant across layers) ----
  hipMemsetAsync(deg12, 0, 2 * 10016 * sizeof(int), stream);
  csr_hist2<<<EB, 256, 0, stream>>>(ei_12 + NE12, ei_21 + NE21, deg12, deg21);
  csr_scan2<<<2, 256, 0, stream>>>(deg12, rowptr12, cur12, PN2, NE12,
                                   deg21, rowptr21, cur21, PN1, NE21);
  csr_scatter2<<<EB, 256, 0, stream>>>(ei_12, ei_12 + NE12, cur12, csr12,
                                       ei_21, ei_21 + NE21, cur21, csr21);

  // ---- input projections + relu (both types, one launch) ----
  gemm_dual<<<2 * NB, 256, 0, stream>>>(x_n1, W_in1, b_in1, x1,
                                        x_n2, W_in2, b_in2, x2,
                                        NB, 0, nullptr, nullptr, nullptr, nullptr, 0);

  for (int l = 0; l < NLAY; ++l) {
    const size_t wo = (size_t)l * 16384;
    const int bo = l * 128;

    fuse_rel4<<<dim3(65, 4), 256, 0, stream>>>(
        Wk_n1 + wo, bk_n1 + bo, a_rel_12 + (size_t)l * 2048,
        Wv_n1 + wo, bv_n1 + bo, m_rel_12 + (size_t)l * 2048,
        Wk_n2 + wo, bk_n2 + bo, a_rel_21 + (size_t)l * 2048,
        Wv_n2 + wo, bv_n2 + bo, m_rel_21 + (size_t)l * 2048,
        WkF1, bkF1, WvF1, bvF1, WkF2, bkF2, WvF2, bvF2);

    kvq_dual<<<2 * NB, 256, 0, stream>>>(
        x1, Wq_n1 + wo, bq_n1 + bo, WkF1, bkF1, WvF1, bvF1, q1, ke1, ve1,
        x2, Wq_n2 + wo, bq_n2 + bo, WkF2, bkF2, WvF2, bvF2, q2, ke2, ve2, NB);

    attn_gather2<<<(2 * PN1) / 4, 256, 0, stream>>>(
        rowptr12, csr12, q2, ke1, ve1, p_rel_12 + l * NH,
        rowptr21, csr21, q1, ke2, ve2, p_rel_21 + l * NH,
        agg2, agg1);

    gemm_dual<<<2 * NB, 256, 0, stream>>>(agg1, Wa_n1 + wo, ba_n1 + bo, x1,
                                          agg2, Wa_n2 + wo, ba_n2 + bo, x2,
                                          NB, 2, skip_n1 + l, skip_n2 + l, Em, Ed, bo);
  }

  // ---- readout ----
  const int DOT_B = (NEF * 16 + 255) / 256;
  edge_dot_bf<<<DOT_B, 256, 0, stream>>>(edge_index, edge_index + NEF, Em, Ed, y, NEF);
}

// Round 5
// 526.757 us; speedup vs baseline: 18.7846x; 1.0041x over previous
//
#include <hip/hip_runtime.h>
#include <cstdint>
#include <cstddef>

typedef unsigned short ushort_t;

// Problem constants
#define PN1   10000
#define PN2   10000
#define NH    8
#define NLAY  2
#define NE12  320000
#define NE21  320000
#define NEF   500000

// ---------- bf16 helpers (RNE) ----------
__device__ __forceinline__ unsigned f2bf(float f) {
  union { float f; unsigned u; } v; v.f = f;
  return (v.u + 0x7FFFu + ((v.u >> 16) & 1u)) >> 16;
}
__device__ __forceinline__ float bf2f(unsigned s) {
  union { float f; unsigned u; } v; v.u = s << 16; return v.f;
}

// ---------- DPP butterfly reduces (pure VALU; no ds_bpermute) ----------
// sum over 8 contiguous lanes (all 8 lanes get the total)
__device__ __forceinline__ float dpp_red8(float x) {
  int t;
  t = __builtin_amdgcn_update_dpp(0, __float_as_int(x), 0xB1,  0xf, 0xf, true); // quad_perm xor1
  x += __int_as_float(t);
  t = __builtin_amdgcn_update_dpp(0, __float_as_int(x), 0x4E,  0xf, 0xf, true); // quad_perm xor2
  x += __int_as_float(t);
  t = __builtin_amdgcn_update_dpp(0, __float_as_int(x), 0x141, 0xf, 0xf, true); // row_half_mirror
  x += __int_as_float(t);
  return x;
}

// ---------- dual-type GEMM: Y[N,128] = act(X @ W + b) ----------
// mode 0: relu   mode 2: skip-blend + bf16 concat write
#define GEMM_ROWS 16
__launch_bounds__(256, 2)
__global__ void gemm_dual(const float* __restrict__ X1, const float* __restrict__ W1,
                          const float* __restrict__ b1, float* __restrict__ Y1,
                          const float* __restrict__ X2, const float* __restrict__ W2,
                          const float* __restrict__ b2, float* __restrict__ Y2,
                          int nb1, int mode,
                          const float* __restrict__ skip1, const float* __restrict__ skip2,
                          ushort_t* __restrict__ cat1, ushort_t* __restrict__ cat2, int catoff)
{
  __shared__ float sW[64 * 128];
  __shared__ float sX[GEMM_ROWS][132];
  const int bid = blockIdx.x;
  const bool t2 = bid >= nb1;
  const float* X = t2 ? X2 : X1;  const float* W = t2 ? W2 : W1;
  const float* bias = t2 ? b2 : b1;  float* Y = t2 ? Y2 : Y1;
  const float* skip = t2 ? skip2 : skip1;
  ushort_t* cat = t2 ? cat2 : cat1;
  const int tid = threadIdx.x;
  const int rowbase = (t2 ? bid - nb1 : bid) * GEMM_ROWS;

#pragma unroll
  for (int i = 0; i < 2; ++i) {
    int idx = tid + i * 256;
    int r = idx >> 5, c4 = (idx & 31) << 2;
    float4 v = *(const float4*)(X + (size_t)(rowbase + r) * 128 + c4);
    sX[r][c4 + 0] = v.x; sX[r][c4 + 1] = v.y;
    sX[r][c4 + 2] = v.z; sX[r][c4 + 3] = v.w;
  }

  const int r0 = (tid >> 5) << 1;
  const int cc = (tid & 31) << 2;
  float acc[2][4] = {{0.f,0.f,0.f,0.f},{0.f,0.f,0.f,0.f}};

  for (int kc = 0; kc < 128; kc += 64) {
    __syncthreads();
#pragma unroll
    for (int i = 0; i < 8; ++i) {
      int idx = tid + i * 256;
      *(float4*)&sW[idx << 2] = *(const float4*)(W + (size_t)kc * 128 + (idx << 2));
    }
    __syncthreads();
#pragma unroll 8
    for (int k = 0; k < 64; ++k) {
      const float4 w = *(const float4*)&sW[(k << 7) + cc];
      const float x0 = sX[r0][kc + k];
      const float x1 = sX[r0 + 1][kc + k];
      acc[0][0] = fmaf(x0, w.x, acc[0][0]); acc[0][1] = fmaf(x0, w.y, acc[0][1]);
      acc[0][2] = fmaf(x0, w.z, acc[0][2]); acc[0][3] = fmaf(x0, w.w, acc[0][3]);
      acc[1][0] = fmaf(x1, w.x, acc[1][0]); acc[1][1] = fmaf(x1, w.y, acc[1][1]);
      acc[1][2] = fmaf(x1, w.z, acc[1][2]); acc[1][3] = fmaf(x1, w.w, acc[1][3]);
    }
  }

  const float4 b4 = *(const float4*)(bias + cc);
  float beta = 0.f;
  if (mode == 2) beta = 1.0f / (1.0f + expf(-skip[0]));
#pragma unroll
  for (int i = 0; i < 2; ++i) {
    int row = rowbase + r0 + i;
    float4 t = make_float4(acc[i][0] + b4.x, acc[i][1] + b4.y,
                           acc[i][2] + b4.z, acc[i][3] + b4.w);
    if (mode == 0) {
      t.x = fmaxf(t.x, 0.f); t.y = fmaxf(t.y, 0.f);
      t.z = fmaxf(t.z, 0.f); t.w = fmaxf(t.w, 0.f);
    } else {
      const float4 xo = *(const float4*)(Y + (size_t)row * 128 + cc);
      t.x = beta * t.x + (1.f - beta) * xo.x;
      t.y = beta * t.y + (1.f - beta) * xo.y;
      t.z = beta * t.z + (1.f - beta) * xo.z;
      t.w = beta * t.w + (1.f - beta) * xo.w;
      uint2 pk;
      pk.x = f2bf(t.x) | (f2bf(t.y) << 16);
      pk.y = f2bf(t.z) | (f2bf(t.w) << 16);
      *(uint2*)(cat + (size_t)row * 256 + catoff + cc) = pk;
    }
    *(float4*)(Y + (size_t)row * 128 + cc) = t;
  }
}

// ---------- dual-type fused K/V/Q projection ----------
__launch_bounds__(256, 2)
__global__ void kvq_dual(const float* __restrict__ X1,
                         const float* __restrict__ Wq1, const float* __restrict__ bq1,
                         const float* __restrict__ Wk1, const float* __restrict__ bk1,
                         const float* __restrict__ Wv1, const float* __restrict__ bv1,
                         float* __restrict__ q1o, ushort_t* __restrict__ ke1, ushort_t* __restrict__ ve1,
                         const float* __restrict__ X2,
                         const float* __restrict__ Wq2, const float* __restrict__ bq2,
                         const float* __restrict__ Wk2, const float* __restrict__ bk2,
                         const float* __restrict__ Wv2, const float* __restrict__ bv2,
                         float* __restrict__ q2o, ushort_t* __restrict__ ke2, ushort_t* __restrict__ ve2,
                         int nb1)
{
  __shared__ float sW[64 * 128];
  __shared__ float sX[GEMM_ROWS][132];
  const int bid = blockIdx.x;
  const bool t2 = bid >= nb1;
  const float* X = t2 ? X2 : X1;
  const float* Ws[3] = { t2 ? Wq2 : Wq1, t2 ? Wk2 : Wk1, t2 ? Wv2 : Wv1 };
  const float* bs[3] = { t2 ? bq2 : bq1, t2 ? bk2 : bk1, t2 ? bv2 : bv1 };
  float* qo = t2 ? q2o : q1o;
  ushort_t* keo = t2 ? ke2 : ke1;
  ushort_t* veo = t2 ? ve2 : ve1;
  const int tid = threadIdx.x;
  const int rowbase = (t2 ? bid - nb1 : bid) * GEMM_ROWS;

#pragma unroll
  for (int i = 0; i < 2; ++i) {
    int idx = tid + i * 256;
    int r = idx >> 5, c4 = (idx & 31) << 2;
    float4 v = *(const float4*)(X + (size_t)(rowbase + r) * 128 + c4);
    sX[r][c4 + 0] = v.x; sX[r][c4 + 1] = v.y;
    sX[r][c4 + 2] = v.z; sX[r][c4 + 3] = v.w;
  }

  const int r0 = (tid >> 5) << 1;
  const int cc = (tid & 31) << 2;
  float acc[3][2][4] = {};

  for (int j = 0; j < 3; ++j) {
    const float* W = Ws[j];
    for (int kc = 0; kc < 128; kc += 64) {
      __syncthreads();
#pragma unroll
      for (int i = 0; i < 8; ++i) {
        int idx = tid + i * 256;
        *(float4*)&sW[idx << 2] = *(const float4*)(W + (size_t)kc * 128 + (idx << 2));
      }
      __syncthreads();
#pragma unroll 8
      for (int k = 0; k < 64; ++k) {
        const float4 w = *(const float4*)&sW[(k << 7) + cc];
        const float x0 = sX[r0][kc + k];
        const float x1 = sX[r0 + 1][kc + k];
        acc[j][0][0] = fmaf(x0, w.x, acc[j][0][0]); acc[j][0][1] = fmaf(x0, w.y, acc[j][0][1]);
        acc[j][0][2] = fmaf(x0, w.z, acc[j][0][2]); acc[j][0][3] = fmaf(x0, w.w, acc[j][0][3]);
        acc[j][1][0] = fmaf(x1, w.x, acc[j][1][0]); acc[j][1][1] = fmaf(x1, w.y, acc[j][1][1]);
        acc[j][1][2] = fmaf(x1, w.z, acc[j][1][2]); acc[j][1][3] = fmaf(x1, w.w, acc[j][1][3]);
      }
    }
  }

#pragma unroll
  for (int j = 0; j < 3; ++j) {
    const float4 b4 = *(const float4*)(bs[j] + cc);
#pragma unroll
    for (int i = 0; i < 2; ++i) {
      int row = rowbase + r0 + i;
      float4 t = make_float4(acc[j][i][0] + b4.x, acc[j][i][1] + b4.y,
                             acc[j][i][2] + b4.z, acc[j][i][3] + b4.w);
      if (j == 0) {
        *(float4*)(qo + (size_t)row * 128 + cc) = t;
      } else {
        uint2 pk;
        pk.x = f2bf(t.x) | (f2bf(t.y) << 16);
        pk.y = f2bf(t.z) | (f2bf(t.w) << 16);
        ushort_t* dst = (j == 1) ? keo : veo;
        *(uint2*)(dst + (size_t)row * 128 + cc) = pk;
      }
    }
  }
}

// ---------- fold per-head relation matrices (4 jobs in one launch) ----------
__global__ void fuse_rel4(const float* Wk1, const float* bk1, const float* a12,
                          const float* Wv1, const float* bv1, const float* m12,
                          const float* Wk2, const float* bk2, const float* a21,
                          const float* Wv2, const float* bv2, const float* m21,
                          float* WkF1, float* bkF1, float* WvF1, float* bvF1,
                          float* WkF2, float* bkF2, float* WvF2, float* bvF2)
{
  const float *W, *b, *rel; float *Wf, *bf;
  switch (blockIdx.y) {
    case 0:  W = Wk1; b = bk1; rel = a12; Wf = WkF1; bf = bkF1; break;
    case 1:  W = Wv1; b = bv1; rel = m12; Wf = WvF1; bf = bvF1; break;
    case 2:  W = Wk2; b = bk2; rel = a21; Wf = WkF2; bf = bkF2; break;
    default: W = Wv2; b = bv2; rel = m21; Wf = WvF2; bf = bvF2; break;
  }
  int idx = blockIdx.x * 256 + threadIdx.x;
  if (idx >= 129 * 128) return;
  int row = idx >> 7, col = idx & 127;
  int h = col >> 4, e = col & 15;
  const float* rr = rel + h * 256;
  const float* src = (row < 128) ? (W + (size_t)row * 128 + h * 16) : (b + h * 16);
  float acc = 0.f;
#pragma unroll
  for (int d = 0; d < 16; ++d) acc = fmaf(src[d], rr[d * 16 + e], acc);
  if (row < 128) Wf[(size_t)row * 128 + col] = acc;
  else           bf[col] = acc;
}

// ---------- CSR build (both graphs) ----------
__global__ void csr_hist2(const int* __restrict__ dst12, const int* __restrict__ dst21,
                          int* __restrict__ deg12, int* __restrict__ deg21)
{
  int e = blockIdx.x * 256 + threadIdx.x;
  if (e < NE12) atomicAdd(&deg12[dst12[e]], 1);
  if (e < NE21) atomicAdd(&deg21[dst21[e]], 1);
}

__global__ void csr_scan2(const int* __restrict__ degA, int* __restrict__ rowptrA,
                          int* __restrict__ cursorA, int NA, int EA,
                          const int* __restrict__ degB, int* __restrict__ rowptrB,
                          int* __restrict__ cursorB, int NB, int EB)
{
  const int* deg = blockIdx.x ? degB : degA;
  int* rowptr = blockIdx.x ? rowptrB : rowptrA;
  int* cursor = blockIdx.x ? cursorB : cursorA;
  const int N = blockIdx.x ? NB : NA;
  const int E = blockIdx.x ? EB : EA;
  __shared__ int part[256];
  const int t = threadIdx.x;
  const int chunk = (N + 255) / 256;
  const int b = t * chunk;
  const int e = (b + chunk < N) ? b + chunk : N;
  int s = 0;
  for (int i = b; i < e; ++i) s += deg[i];
  part[t] = s;
  __syncthreads();
  if (t == 0) {
    int run = 0;
    for (int i = 0; i < 256; ++i) { int v = part[i]; part[i] = run; run += v; }
  }
  __syncthreads();
  int run = part[t];
  for (int i = b; i < e; ++i) { rowptr[i] = run; cursor[i] = run; run += deg[i]; }
  if (t == 0) rowptr[N] = E;
}

__global__ void csr_scatter2(const int* __restrict__ src12, const int* __restrict__ dst12,
                             int* __restrict__ cur12, int* __restrict__ csr12,
                             const int* __restrict__ src21, const int* __restrict__ dst21,
                             int* __restrict__ cur21, int* __restrict__ csr21)
{
  int e = blockIdx.x * 256 + threadIdx.x;
  if (e < NE12) { int p = atomicAdd(&cur12[dst12[e]], 1); csr12[p] = src12[e]; }
  if (e < NE21) { int p = atomicAdd(&cur21[dst21[e]], 1); csr21[p] = src21[e]; }
}

// ---------- fused gather attention, both directions, bf16 tables ----------
// one wave per dst node; 2 channels per lane; 4-edge software pipeline;
// DPP butterfly for the 8-lane head reduce (no ds_bpermute).
// No max-subtraction: |alpha| << 1, exp cannot overflow; iterations independent.
__launch_bounds__(256)
__global__ void attn_gather2(const int* __restrict__ rowptr12, const int* __restrict__ csr12,
                             const float* __restrict__ q2, const ushort_t* __restrict__ ke1,
                             const ushort_t* __restrict__ ve1, const float* __restrict__ pr12,
                             const int* __restrict__ rowptr21, const int* __restrict__ csr21,
                             const float* __restrict__ q1, const ushort_t* __restrict__ ke2,
                             const ushort_t* __restrict__ ve2, const float* __restrict__ pr21,
                             float* __restrict__ agg2, float* __restrict__ agg1)
{
  const int wid = (blockIdx.x * 256 + threadIdx.x) >> 6;
  const int lane = threadIdx.x & 63;
  const bool dirB = wid >= PN2;
  const int d = dirB ? wid - PN2 : wid;
  const int* rowptr = dirB ? rowptr21 : rowptr12;
  const int* csr    = dirB ? csr21 : csr12;
  const float* q    = dirB ? q1 : q2;
  const ushort_t* ke = dirB ? ke2 : ke1;
  const ushort_t* ve = dirB ? ve2 : ve1;
  const float* prel = dirB ? pr21 : pr12;
  float* agg = dirB ? agg1 : agg2;

  const int h = lane >> 3;
  const float2 qv = *(const float2*)(q + (size_t)d * 128 + 2 * lane);
  const float pr = prel[h] * 0.25f;     // p_rel / sqrt(16)
  const int beg = rowptr[d], end = rowptr[d + 1];
  const int co = 2 * lane;

  float ssum = 0.f, a0 = 0.f, a1 = 0.f;

  // 4-edge pipeline buffers
  unsigned kk[4] = {0,0,0,0}, vv[4] = {0,0,0,0};
#pragma unroll
  for (int j = 0; j < 4; ++j) {
    if (beg + j < end) {
      int s = csr[beg + j];
      kk[j] = *(const unsigned*)(ke + (size_t)s * 128 + co);
      vv[j] = *(const unsigned*)(ve + (size_t)s * 128 + co);
    }
  }

  for (int i = beg; i < end; i += 4) {
    unsigned kc[4], vc[4];
#pragma unroll
    for (int j = 0; j < 4; ++j) { kc[j] = kk[j]; vc[j] = vv[j]; }
    // prefetch next 4 edges
#pragma unroll
    for (int j = 0; j < 4; ++j) {
      int idx = i + 4 + j;
      if (idx < end) {
        int s = csr[idx];
        kk[j] = *(const unsigned*)(ke + (size_t)s * 128 + co);
        vv[j] = *(const unsigned*)(ve + (size_t)s * 128 + co);
      }
    }
    float p[4], ex[4];
#pragma unroll
    for (int j = 0; j < 4; ++j)
      p[j] = fmaf(qv.x, bf2f(kc[j] & 0xffffu), qv.y * bf2f(kc[j] >> 16));
#pragma unroll
    for (int j = 0; j < 4; ++j) p[j] = dpp_red8(p[j]);
#pragma unroll
    for (int j = 0; j < 4; ++j)
      ex[j] = (i + j < end) ? __expf(p[j] * pr) : 0.f;
    ssum += (ex[0] + ex[1]) + (ex[2] + ex[3]);
#pragma unroll
    for (int j = 0; j < 4; ++j) {
      a0 = fmaf(ex[j], bf2f(vc[j] & 0xffffu), a0);
      a1 = fmaf(ex[j], bf2f(vc[j] >> 16),     a1);
    }
  }

  const float inv = 1.0f / (ssum + 1e-16f);
  float o0 = a0 * inv;
  float o1 = a1 * inv;
  o0 = 0.5f * o0 * (1.f + erff(o0 * 0.70710678118654752f));
  o1 = 0.5f * o1 * (1.f + erff(o1 * 0.70710678118654752f));
  float2 out; out.x = o0; out.y = o1;
  *(float2*)(agg + (size_t)d * 128 + co) = out;
}

// ---------- readout on bf16 Em/Ed: 8 lanes per edge, DPP reduce ----------
__launch_bounds__(256)
__global__ void edge_dot_bf(const int* __restrict__ mi, const int* __restrict__ di,
                            const ushort_t* __restrict__ Em, const ushort_t* __restrict__ Ed,
                            float* __restrict__ y, int E)
{
  int t = blockIdx.x * 256 + threadIdx.x;
  int e = t >> 3;                          // 8 lanes per edge
  int l = t & 7;
  if (e >= E) return;
  int m = mi[e], d = di[e];
  const uint4* A = (const uint4*)(Em + (size_t)m * 256);   // 32 uint4 per row
  const uint4* B = (const uint4*)(Ed + (size_t)d * 256);
  float acc = 0.f;
#pragma unroll
  for (int i = 0; i < 4; ++i) {
    uint4 a = A[l + 8 * i];
    uint4 b = B[l + 8 * i];
    acc = fmaf(bf2f(a.x & 0xffffu), bf2f(b.x & 0xffffu), acc);
    acc = fmaf(bf2f(a.x >> 16),     bf2f(b.x >> 16),     acc);
    acc = fmaf(bf2f(a.y & 0xffffu), bf2f(b.y & 0xffffu), acc);
    acc = fmaf(bf2f(a.y >> 16),     bf2f(b.y >> 16),     acc);
    acc = fmaf(bf2f(a.z & 0xffffu), bf2f(b.z & 0xffffu), acc);
    acc = fmaf(bf2f(a.z >> 16),     bf2f(b.z >> 16),     acc);
    acc = fmaf(bf2f(a.w & 0xffffu), bf2f(b.w & 0xffffu), acc);
    acc = fmaf(bf2f(a.w >> 16),     bf2f(b.w >> 16),     acc);
  }
  acc = dpp_red8(acc);
  if (l == 0) y[e] = acc;
}

// ---------- launch ----------
extern "C" void kernel_launch(void* const* d_in, const int* in_sizes, int n_in,
                              void* d_out, int out_size, void* d_ws, size_t ws_size,
                              hipStream_t stream)
{
  const float* x_n1  = (const float*)d_in[0];
  const float* x_n2  = (const float*)d_in[1];
  const float* W_in1 = (const float*)d_in[2];
  const float* b_in1 = (const float*)d_in[3];
  const float* W_in2 = (const float*)d_in[4];
  const float* b_in2 = (const float*)d_in[5];
  const float* Wk_n1 = (const float*)d_in[6];
  const float* bk_n1 = (const float*)d_in[7];
  const float* Wq_n1 = (const float*)d_in[8];
  const float* bq_n1 = (const float*)d_in[9];
  const float* Wv_n1 = (const float*)d_in[10];
  const float* bv_n1 = (const float*)d_in[11];
  const float* Wa_n1 = (const float*)d_in[12];
  const float* ba_n1 = (const float*)d_in[13];
  const float* skip_n1 = (const float*)d_in[14];
  const float* Wk_n2 = (const float*)d_in[15];
  const float* bk_n2 = (const float*)d_in[16];
  const float* Wq_n2 = (const float*)d_in[17];
  const float* bq_n2 = (const float*)d_in[18];
  const float* Wv_n2 = (const float*)d_in[19];
  const float* bv_n2 = (const float*)d_in[20];
  const float* Wa_n2 = (const float*)d_in[21];
  const float* ba_n2 = (const float*)d_in[22];
  const float* skip_n2 = (const float*)d_in[23];
  const float* a_rel_12 = (const float*)d_in[24];
  const float* m_rel_12 = (const float*)d_in[25];
  const float* p_rel_12 = (const float*)d_in[26];
  const float* a_rel_21 = (const float*)d_in[27];
  const float* m_rel_21 = (const float*)d_in[28];
  const float* p_rel_21 = (const float*)d_in[29];
  const int*   ei_12 = (const int*)d_in[30];
  const int*   ei_21 = (const int*)d_in[31];
  const int*   edge_index = (const int*)d_in[32];
  float* y = (float*)d_out;

  // ---- workspace carve-up (float units) ----
  const size_t NF = (size_t)PN1 * 128;       // 1,280,000
  float* ws = (float*)d_ws;
  float* x1   = ws + 0 * NF;
  float* x2   = ws + 1 * NF;
  float* q1   = ws + 2 * NF;
  float* q2   = ws + 3 * NF;
  float* agg1 = ws + 4 * NF;
  float* agg2 = ws + 5 * NF;
  ushort_t* ke1 = (ushort_t*)(ws + 6 * NF);              // [N,128] bf16
  ushort_t* ve1 = (ushort_t*)(ws + 6 * NF +  640000);
  ushort_t* ke2 = (ushort_t*)(ws + 6 * NF + 1280000);
  ushort_t* ve2 = (ushort_t*)(ws + 6 * NF + 1920000);
  ushort_t* Em  = (ushort_t*)(ws + 6 * NF + 2560000);    // [N1,256] bf16
  ushort_t* Ed  = (ushort_t*)(ws + 6 * NF + 3840000);
  float* WkF1 = ws + 6 * NF + 5120000;  float* bkF1 = WkF1 + 16384;
  float* WvF1 = WkF1 + 16512;           float* bvF1 = WvF1 + 16384;
  float* WkF2 = WvF1 + 16512;           float* bkF2 = WkF2 + 16384;
  float* WvF2 = WkF2 + 16512;           float* bvF2 = WvF2 + 16384;
  int* ip = (int*)(WvF2 + 16512);
  int* rowptr12 = ip;                   // 10016 each
  int* rowptr21 = ip + 10016;
  int* cur12    = ip + 20032;
  int* cur21    = ip + 30048;
  int* deg12    = ip + 40064;
  int* deg21    = ip + 50080;
  int* csr12    = ip + 60096;
  int* csr21    = ip + 60096 + NE12;

  const int NB = PN1 / GEMM_ROWS;            // 625 blocks per type
  const int EB = (NE12 + 255) / 256;         // 1250

  // ---- CSR build (graph constant across layers) ----
  hipMemsetAsync(deg12, 0, 2 * 10016 * sizeof(int), stream);
  csr_hist2<<<EB, 256, 0, stream>>>(ei_12 + NE12, ei_21 + NE21, deg12, deg21);
  csr_scan2<<<2, 256, 0, stream>>>(deg12, rowptr12, cur12, PN2, NE12,
                                   deg21, rowptr21, cur21, PN1, NE21);
  csr_scatter2<<<EB, 256, 0, stream>>>(ei_12, ei_12 + NE12, cur12, csr12,
                                       ei_21, ei_21 + NE21, cur21, csr21);

  // ---- input projections + relu (both types, one launch) ----
  gemm_dual<<<2 * NB, 256, 0, stream>>>(x_n1, W_in1, b_in1, x1,
                                        x_n2, W_in2, b_in2, x2,
                                        NB, 0, nullptr, nullptr, nullptr, nullptr, 0);

  for (int l = 0; l < NLAY; ++l) {
    const size_t wo = (size_t)l * 16384;
    const int bo = l * 128;

    fuse_rel4<<<dim3(65, 4), 256, 0, stream>>>(
        Wk_n1 + wo, bk_n1 + bo, a_rel_12 + (size_t)l * 2048,
        Wv_n1 + wo, bv_n1 + bo, m_rel_12 + (size_t)l * 2048,
        Wk_n2 + wo, bk_n2 + bo, a_rel_21 + (size_t)l * 2048,
        Wv_n2 + wo, bv_n2 + bo, m_rel_21 + (size_t)l * 2048,
        WkF1, bkF1, WvF1, bvF1, WkF2, bkF2, WvF2, bvF2);

    kvq_dual<<<2 * NB, 256, 0, stream>>>(
        x1, Wq_n1 + wo, bq_n1 + bo, WkF1, bkF1, WvF1, bvF1, q1, ke1, ve1,
        x2, Wq_n2 + wo, bq_n2 + bo, WkF2, bkF2, WvF2, bvF2, q2, ke2, ve2, NB);

    attn_gather2<<<(2 * PN1) / 4, 256, 0, stream>>>(
        rowptr12, csr12, q2, ke1, ve1, p_rel_12 + l * NH,
        rowptr21, csr21, q1, ke2, ve2, p_rel_21 + l * NH,
        agg2, agg1);

    gemm_dual<<<2 * NB, 256, 0, stream>>>(agg1, Wa_n1 + wo, ba_n1 + bo, x1,
                                          agg2, Wa_n2 + wo, ba_n2 + bo, x2,
                                          NB, 2, skip_n1 + l, skip_n2 + l, Em, Ed, bo);
  }

  // ---- readout ----
  const int DOT_B = (NEF * 8 + 255) / 256;   // 15625
  edge_dot_bf<<<DOT_B, 256, 0, stream>>>(edge_index, edge_index + NEF, Em, Ed, y, NEF);
}

// Round 7
// 504.331 us; speedup vs baseline: 19.6198x; 1.0445x over previous
//
#include <hip/hip_runtime.h>
#include <cstdint>
#include <cstddef>

typedef unsigned short ushort_t;

// Problem constants
#define PN1   10000
#define PN2   10000
#define NH    8
#define NLAY  2
#define NE12  320000
#define NE21  320000
#define NEF   500000

// ---------- bf16 helpers (RNE) ----------
__device__ __forceinline__ unsigned f2bf(float f) {
  union { float f; unsigned u; } v; v.f = f;
  return (v.u + 0x7FFFu + ((v.u >> 16) & 1u)) >> 16;
}
__device__ __forceinline__ float bf2f(unsigned s) {
  union { float f; unsigned u; } v; v.u = s << 16; return v.f;
}

// ---------- DPP butterfly: sum over 8 contiguous lanes ----------
__device__ __forceinline__ float dpp_red8(float x) {
  int t;
  t = __builtin_amdgcn_update_dpp(0, __float_as_int(x), 0xB1,  0xf, 0xf, true);
  x += __int_as_float(t);
  t = __builtin_amdgcn_update_dpp(0, __float_as_int(x), 0x4E,  0xf, 0xf, true);
  x += __int_as_float(t);
  t = __builtin_amdgcn_update_dpp(0, __float_as_int(x), 0x141, 0xf, 0xf, true);
  x += __int_as_float(t);
  return x;
}

// ---------- dual-type GEMM: Y[N,128] = act(X @ W + b) ----------
// 32 rows/block, 4x4 outputs/thread, X staged transposed.
// sXT pad = 36 floats (144 B): keeps &sXT[k][r0] 16B-aligned for b128 reads.
// mode 0: relu   mode 2: skip-blend + bf16 concat write
#define GR 32
__launch_bounds__(256, 2)
__global__ void gemm_dual(const float* __restrict__ X1, const float* __restrict__ W1,
                          const float* __restrict__ b1, float* __restrict__ Y1,
                          const float* __restrict__ X2, const float* __restrict__ W2,
                          const float* __restrict__ b2, float* __restrict__ Y2,
                          int nb1, int N, int mode,
                          const float* __restrict__ skip1, const float* __restrict__ skip2,
                          ushort_t* __restrict__ cat1, ushort_t* __restrict__ cat2, int catoff)
{
  __shared__ float sW[64 * 128];
  __shared__ float sXT[128][36];          // transposed X tile: [k][row], 16B-aligned rows
  const int bid = blockIdx.x;
  const bool t2 = bid >= nb1;
  const float* X = t2 ? X2 : X1;  const float* W = t2 ? W2 : W1;
  const float* bias = t2 ? b2 : b1;  float* Y = t2 ? Y2 : Y1;
  const float* skip = t2 ? skip2 : skip1;
  ushort_t* cat = t2 ? cat2 : cat1;
  const int tid = threadIdx.x;
  const int rowbase = (t2 ? bid - nb1 : bid) * GR;

  // stage X tile transposed: 32 rows x 128 cols
#pragma unroll
  for (int i = 0; i < 4; ++i) {
    int idx = tid + i * 256;              // 0..1023 float4s
    int r = idx >> 5, c4 = (idx & 31) << 2;
    int gr = rowbase + r;
    float4 v = make_float4(0.f, 0.f, 0.f, 0.f);
    if (gr < N) v = *(const float4*)(X + (size_t)gr * 128 + c4);
    sXT[c4 + 0][r] = v.x; sXT[c4 + 1][r] = v.y;
    sXT[c4 + 2][r] = v.z; sXT[c4 + 3][r] = v.w;
  }

  const int r0 = (tid >> 5) << 2;         // 4 rows per thread
  const int cc = (tid & 31) << 2;         // 4 cols per thread
  float acc[4][4] = {};

  for (int kc = 0; kc < 128; kc += 64) {
    __syncthreads();
#pragma unroll
    for (int i = 0; i < 8; ++i) {
      int idx = tid + i * 256;
      *(float4*)&sW[idx << 2] = *(const float4*)(W + (size_t)kc * 128 + (idx << 2));
    }
    __syncthreads();
#pragma unroll 16
    for (int k = 0; k < 64; ++k) {
      const float4 w = *(const float4*)&sW[(k << 7) + cc];
      const float4 x = *(const float4*)&sXT[kc + k][r0];
      acc[0][0] = fmaf(x.x, w.x, acc[0][0]); acc[0][1] = fmaf(x.x, w.y, acc[0][1]);
      acc[0][2] = fmaf(x.x, w.z, acc[0][2]); acc[0][3] = fmaf(x.x, w.w, acc[0][3]);
      acc[1][0] = fmaf(x.y, w.x, acc[1][0]); acc[1][1] = fmaf(x.y, w.y, acc[1][1]);
      acc[1][2] = fmaf(x.y, w.z, acc[1][2]); acc[1][3] = fmaf(x.y, w.w, acc[1][3]);
      acc[2][0] = fmaf(x.z, w.x, acc[2][0]); acc[2][1] = fmaf(x.z, w.y, acc[2][1]);
      acc[2][2] = fmaf(x.z, w.z, acc[2][2]); acc[2][3] = fmaf(x.z, w.w, acc[2][3]);
      acc[3][0] = fmaf(x.w, w.x, acc[3][0]); acc[3][1] = fmaf(x.w, w.y, acc[3][1]);
      acc[3][2] = fmaf(x.w, w.z, acc[3][2]); acc[3][3] = fmaf(x.w, w.w, acc[3][3]);
    }
  }

  const float4 b4 = *(const float4*)(bias + cc);
  float beta = 0.f;
  if (mode == 2) beta = 1.0f / (1.0f + expf(-skip[0]));
#pragma unroll
  for (int i = 0; i < 4; ++i) {
    int row = rowbase + r0 + i;
    if (row >= N) continue;
    float4 t = make_float4(acc[i][0] + b4.x, acc[i][1] + b4.y,
                           acc[i][2] + b4.z, acc[i][3] + b4.w);
    if (mode == 0) {
      t.x = fmaxf(t.x, 0.f); t.y = fmaxf(t.y, 0.f);
      t.z = fmaxf(t.z, 0.f); t.w = fmaxf(t.w, 0.f);
    } else {
      const float4 xo = *(const float4*)(Y + (size_t)row * 128 + cc);
      t.x = beta * t.x + (1.f - beta) * xo.x;
      t.y = beta * t.y + (1.f - beta) * xo.y;
      t.z = beta * t.z + (1.f - beta) * xo.z;
      t.w = beta * t.w + (1.f - beta) * xo.w;
      uint2 pk;
      pk.x = f2bf(t.x) | (f2bf(t.y) << 16);
      pk.y = f2bf(t.z) | (f2bf(t.w) << 16);
      *(uint2*)(cat + (size_t)row * 256 + catoff + cc) = pk;
    }
    *(float4*)(Y + (size_t)row * 128 + cc) = t;
  }
}

// ---------- dual-type fused K/V/Q projection ----------
// q out fp32; k/v packed bf16 into ONE interleaved table:
// row = 128 uints; uint[2p] = k channels (2p,2p+1), uint[2p+1] = v channels (2p,2p+1)
__launch_bounds__(256, 2)
__global__ void kvq_dual(const float* __restrict__ X1,
                         const float* __restrict__ Wq1, const float* __restrict__ bq1,
                         const float* __restrict__ Wk1, const float* __restrict__ bk1,
                         const float* __restrict__ Wv1, const float* __restrict__ bv1,
                         float* __restrict__ q1o, unsigned* __restrict__ kv1,
                         const float* __restrict__ X2,
                         const float* __restrict__ Wq2, const float* __restrict__ bq2,
                         const float* __restrict__ Wk2, const float* __restrict__ bk2,
                         const float* __restrict__ Wv2, const float* __restrict__ bv2,
                         float* __restrict__ q2o, unsigned* __restrict__ kv2,
                         int nb1, int N)
{
  __shared__ float sW[64 * 128];
  __shared__ float sXT[128][36];
  const int bid = blockIdx.x;
  const bool t2 = bid >= nb1;
  const float* X = t2 ? X2 : X1;
  const float* Ws[3] = { t2 ? Wq2 : Wq1, t2 ? Wk2 : Wk1, t2 ? Wv2 : Wv1 };
  const float* bs[3] = { t2 ? bq2 : bq1, t2 ? bk2 : bk1, t2 ? bv2 : bv1 };
  float* qo = t2 ? q2o : q1o;
  unsigned* kvo = t2 ? kv2 : kv1;
  const int tid = threadIdx.x;
  const int rowbase = (t2 ? bid - nb1 : bid) * GR;

#pragma unroll
  for (int i = 0; i < 4; ++i) {
    int idx = tid + i * 256;
    int r = idx >> 5, c4 = (idx & 31) << 2;
    int gr = rowbase + r;
    float4 v = make_float4(0.f, 0.f, 0.f, 0.f);
    if (gr < N) v = *(const float4*)(X + (size_t)gr * 128 + c4);
    sXT[c4 + 0][r] = v.x; sXT[c4 + 1][r] = v.y;
    sXT[c4 + 2][r] = v.z; sXT[c4 + 3][r] = v.w;
  }

  const int r0 = (tid >> 5) << 2;
  const int cc = (tid & 31) << 2;
  float acc[3][4][4] = {};

  for (int j = 0; j < 3; ++j) {
    const float* W = Ws[j];
    for (int kc = 0; kc < 128; kc += 64) {
      __syncthreads();
#pragma unroll
      for (int i = 0; i < 8; ++i) {
        int idx = tid + i * 256;
        *(float4*)&sW[idx << 2] = *(const float4*)(W + (size_t)kc * 128 + (idx << 2));
      }
      __syncthreads();
#pragma unroll 16
      for (int k = 0; k < 64; ++k) {
        const float4 w = *(const float4*)&sW[(k << 7) + cc];
        const float4 x = *(const float4*)&sXT[kc + k][r0];
        acc[j][0][0] = fmaf(x.x, w.x, acc[j][0][0]); acc[j][0][1] = fmaf(x.x, w.y, acc[j][0][1]);
        acc[j][0][2] = fmaf(x.x, w.z, acc[j][0][2]); acc[j][0][3] = fmaf(x.x, w.w, acc[j][0][3]);
        acc[j][1][0] = fmaf(x.y, w.x, acc[j][1][0]); acc[j][1][1] = fmaf(x.y, w.y, acc[j][1][1]);
        acc[j][1][2] = fmaf(x.y, w.z, acc[j][1][2]); acc[j][1][3] = fmaf(x.y, w.w, acc[j][1][3]);
        acc[j][2][0] = fmaf(x.z, w.x, acc[j][2][0]); acc[j][2][1] = fmaf(x.z, w.y, acc[j][2][1]);
        acc[j][2][2] = fmaf(x.z, w.z, acc[j][2][2]); acc[j][2][3] = fmaf(x.z, w.w, acc[j][2][3]);
        acc[j][3][0] = fmaf(x.w, w.x, acc[j][3][0]); acc[j][3][1] = fmaf(x.w, w.y, acc[j][3][1]);
        acc[j][3][2] = fmaf(x.w, w.z, acc[j][3][2]); acc[j][3][3] = fmaf(x.w, w.w, acc[j][3][3]);
      }
    }
  }

#pragma unroll
  for (int j = 0; j < 3; ++j) {
    const float4 b4 = *(const float4*)(bs[j] + cc);
#pragma unroll
    for (int i = 0; i < 4; ++i) {
      int row = rowbase + r0 + i;
      if (row >= N) continue;
      float4 t = make_float4(acc[j][i][0] + b4.x, acc[j][i][1] + b4.y,
                             acc[j][i][2] + b4.z, acc[j][i][3] + b4.w);
      if (j == 0) {
        *(float4*)(qo + (size_t)row * 128 + cc) = t;
      } else {
        unsigned pk0 = f2bf(t.x) | (f2bf(t.y) << 16);
        unsigned pk1 = f2bf(t.z) | (f2bf(t.w) << 16);
        unsigned* kvrow = kvo + (size_t)row * 128;
        if (j == 1) { kvrow[cc] = pk0;     kvrow[cc + 2] = pk1; }
        else        { kvrow[cc + 1] = pk0; kvrow[cc + 3] = pk1; }
      }
    }
  }
}

// ---------- fold per-head relation matrices (4 jobs in one launch) ----------
__global__ void fuse_rel4(const float* Wk1, const float* bk1, const float* a12,
                          const float* Wv1, const float* bv1, const float* m12,
                          const float* Wk2, const float* bk2, const float* a21,
                          const float* Wv2, const float* bv2, const float* m21,
                          float* WkF1, float* bkF1, float* WvF1, float* bvF1,
                          float* WkF2, float* bkF2, float* WvF2, float* bvF2)
{
  const float *W, *b, *rel; float *Wf, *bf;
  switch (blockIdx.y) {
    case 0:  W = Wk1; b = bk1; rel = a12; Wf = WkF1; bf = bkF1; break;
    case 1:  W = Wv1; b = bv1; rel = m12; Wf = WvF1; bf = bvF1; break;
    case 2:  W = Wk2; b = bk2; rel = a21; Wf = WkF2; bf = bkF2; break;
    default: W = Wv2; b = bv2; rel = m21; Wf = WvF2; bf = bvF2; break;
  }
  int idx = blockIdx.x * 256 + threadIdx.x;
  if (idx >= 129 * 128) return;
  int row = idx >> 7, col = idx & 127;
  int h = col >> 4, e = col & 15;
  const float* rr = rel + h * 256;
  const float* src = (row < 128) ? (W + (size_t)row * 128 + h * 16) : (b + h * 16);
  float acc = 0.f;
#pragma unroll
  for (int d = 0; d < 16; ++d) acc = fmaf(src[d], rr[d * 16 + e], acc);
  if (row < 128) Wf[(size_t)row * 128 + col] = acc;
  else           bf[col] = acc;
}

// ---------- CSR build (both graphs) ----------
__global__ void csr_hist2(const int* __restrict__ dst12, const int* __restrict__ dst21,
                          int* __restrict__ deg12, int* __restrict__ deg21)
{
  int e = blockIdx.x * 256 + threadIdx.x;
  if (e < NE12) atomicAdd(&deg12[dst12[e]], 1);
  if (e < NE21) atomicAdd(&deg21[dst21[e]], 1);
}

__global__ void csr_scan2(const int* __restrict__ degA, int* __restrict__ rowptrA,
                          int* __restrict__ cursorA, int NA, int EA,
                          const int* __restrict__ degB, int* __restrict__ rowptrB,
                          int* __restrict__ cursorB, int NB, int EB)
{
  const int* deg = blockIdx.x ? degB : degA;
  int* rowptr = blockIdx.x ? rowptrB : rowptrA;
  int* cursor = blockIdx.x ? cursorB : cursorA;
  const int N = blockIdx.x ? NB : NA;
  const int E = blockIdx.x ? EB : EA;
  __shared__ int part[256];
  const int t = threadIdx.x;
  const int chunk = (N + 255) / 256;
  const int b = t * chunk;
  const int e = (b + chunk < N) ? b + chunk : N;
  int s = 0;
  for (int i = b; i < e; ++i) s += deg[i];
  part[t] = s;
  __syncthreads();
  if (t == 0) {
    int run = 0;
    for (int i = 0; i < 256; ++i) { int v = part[i]; part[i] = run; run += v; }
  }
  __syncthreads();
  int run = part[t];
  for (int i = b; i < e; ++i) { rowptr[i] = run; cursor[i] = run; run += deg[i]; }
  if (t == 0) rowptr[N] = E;
}

__global__ void csr_scatter2(const int* __restrict__ src12, const int* __restrict__ dst12,
                             int* __restrict__ cur12, int* __restrict__ csr12,
                             const int* __restrict__ src21, const int* __restrict__ dst21,
                             int* __restrict__ cur21, int* __restrict__ csr21)
{
  int e = blockIdx.x * 256 + threadIdx.x;
  if (e < NE12) { int p = atomicAdd(&cur12[dst12[e]], 1); csr12[p] = src12[e]; }
  if (e < NE21) { int p = atomicAdd(&cur21[dst21[e]], 1); csr21[p] = src21[e]; }
}

// ---------- fused gather attention, both directions ----------
// one wave per dst node; 2 channels/lane; interleaved kv table (one dwordx2
// per edge); node index forced wave-uniform via readfirstlane so the gather
// address path is SALU; 8-edge software pipeline.
__launch_bounds__(256)
__global__ void attn_gather2(const int* __restrict__ rowptr12, const int* __restrict__ csr12,
                             const float* __restrict__ q2, const unsigned* __restrict__ kv1,
                             const float* __restrict__ pr12,
                             const int* __restrict__ rowptr21, const int* __restrict__ csr21,
                             const float* __restrict__ q1, const unsigned* __restrict__ kv2,
                             const float* __restrict__ pr21,
                             float* __restrict__ agg2, float* __restrict__ agg1)
{
  const int wid = (blockIdx.x * 256 + threadIdx.x) >> 6;
  const int lane = threadIdx.x & 63;
  const bool dirB = wid >= PN2;
  const int d = __builtin_amdgcn_readfirstlane(dirB ? wid - PN2 : wid);
  const int* rowptr = dirB ? rowptr21 : rowptr12;
  const int* csr    = dirB ? csr21 : csr12;
  const float* q    = dirB ? q1 : q2;
  const unsigned* kv = dirB ? kv2 : kv1;
  const float* prel = dirB ? pr21 : pr12;
  float* agg = dirB ? agg1 : agg2;

  const int h = lane >> 3;
  const float2 qv = *(const float2*)(q + (size_t)d * 128 + 2 * lane);
  const float pr = prel[h] * 0.25f;     // p_rel / sqrt(16)
  const int beg = __builtin_amdgcn_readfirstlane(rowptr[d]);
  const int end = __builtin_amdgcn_readfirstlane(rowptr[d + 1]);
  const int co = 2 * lane;              // uint index within kv row; ALSO float offset in q/agg

  float ssum = 0.f, a0 = 0.f, a1 = 0.f;

  uint2 buf[8];
#pragma unroll
  for (int j = 0; j < 8; ++j) {
    buf[j] = make_uint2(0u, 0u);
    if (beg + j < end) {
      int s = __builtin_amdgcn_readfirstlane(csr[beg + j]);
      buf[j] = *(const uint2*)(kv + (size_t)s * 128 + co);
    }
  }

  for (int i = beg; i < end; i += 8) {
    uint2 cur[8];
#pragma unroll
    for (int j = 0; j < 8; ++j) cur[j] = buf[j];
#pragma unroll
    for (int j = 0; j < 8; ++j) {
      int idx = i + 8 + j;
      if (idx < end) {
        int s = __builtin_amdgcn_readfirstlane(csr[idx]);
        buf[j] = *(const uint2*)(kv + (size_t)s * 128 + co);
      }
    }
    float p[8], ex[8];
#pragma unroll
    for (int j = 0; j < 8; ++j)
      p[j] = fmaf(qv.x, bf2f(cur[j].x & 0xffffu), qv.y * bf2f(cur[j].x >> 16));
#pragma unroll
    for (int j = 0; j < 8; ++j) p[j] = dpp_red8(p[j]);
#pragma unroll
    for (int j = 0; j < 8; ++j)
      ex[j] = (i + j < end) ? __expf(p[j] * pr) : 0.f;
    ssum += ((ex[0] + ex[1]) + (ex[2] + ex[3])) + ((ex[4] + ex[5]) + (ex[6] + ex[7]));
#pragma unroll
    for (int j = 0; j < 8; ++j) {
      a0 = fmaf(ex[j], bf2f(cur[j].y & 0xffffu), a0);
      a1 = fmaf(ex[j], bf2f(cur[j].y >> 16),     a1);
    }
  }

  const float inv = 1.0f / (ssum + 1e-16f);
  float o0 = a0 * inv;
  float o1 = a1 * inv;
  o0 = 0.5f * o0 * (1.f + erff(o0 * 0.70710678118654752f));
  o1 = 0.5f * o1 * (1.f + erff(o1 * 0.70710678118654752f));
  float2 out; out.x = o0; out.y = o1;
  *(float2*)(agg + (size_t)d * 128 + co) = out;   // FIX: float offset is co (= 2*lane)
}

// ---------- readout on bf16 Em/Ed: 8 lanes per edge, DPP reduce ----------
__launch_bounds__(256)
__global__ void edge_dot_bf(const int* __restrict__ mi, const int* __restrict__ di,
                            const ushort_t* __restrict__ Em, const ushort_t* __restrict__ Ed,
                            float* __restrict__ y, int E)
{
  int t = blockIdx.x * 256 + threadIdx.x;
  int e = t >> 3;                          // 8 lanes per edge
  int l = t & 7;
  if (e >= E) return;
  int m = mi[e], d = di[e];
  const uint4* A = (const uint4*)(Em + (size_t)m * 256);
  const uint4* B = (const uint4*)(Ed + (size_t)d * 256);
  float acc = 0.f;
#pragma unroll
  for (int i = 0; i < 4; ++i) {
    uint4 a = A[l + 8 * i];
    uint4 b = B[l + 8 * i];
    acc = fmaf(bf2f(a.x & 0xffffu), bf2f(b.x & 0xffffu), acc);
    acc = fmaf(bf2f(a.x >> 16),     bf2f(b.x >> 16),     acc);
    acc = fmaf(bf2f(a.y & 0xffffu), bf2f(b.y & 0xffffu), acc);
    acc = fmaf(bf2f(a.y >> 16),     bf2f(b.y >> 16),     acc);
    acc = fmaf(bf2f(a.z & 0xffffu), bf2f(b.z & 0xffffu), acc);
    acc = fmaf(bf2f(a.z >> 16),     bf2f(b.z >> 16),     acc);
    acc = fmaf(bf2f(a.w & 0xffffu), bf2f(b.w & 0xffffu), acc);
    acc = fmaf(bf2f(a.w >> 16),     bf2f(b.w >> 16),     acc);
  }
  acc = dpp_red8(acc);
  if (l == 0) y[e] = acc;
}

// ---------- launch ----------
extern "C" void kernel_launch(void* const* d_in, const int* in_sizes, int n_in,
                              void* d_out, int out_size, void* d_ws, size_t ws_size,
                              hipStream_t stream)
{
  const float* x_n1  = (const float*)d_in[0];
  const float* x_n2  = (const float*)d_in[1];
  const float* W_in1 = (const float*)d_in[2];
  const float* b_in1 = (const float*)d_in[3];
  const float* W_in2 = (const float*)d_in[4];
  const float* b_in2 = (const float*)d_in[5];
  const float* Wk_n1 = (const float*)d_in[6];
  const float* bk_n1 = (const float*)d_in[7];
  const float* Wq_n1 = (const float*)d_in[8];
  const float* bq_n1 = (const float*)d_in[9];
  const float* Wv_n1 = (const float*)d_in[10];
  const float* bv_n1 = (const float*)d_in[11];
  const float* Wa_n1 = (const float*)d_in[12];
  const float* ba_n1 = (const float*)d_in[13];
  const float* skip_n1 = (const float*)d_in[14];
  const float* Wk_n2 = (const float*)d_in[15];
  const float* bk_n2 = (const float*)d_in[16];
  const float* Wq_n2 = (const float*)d_in[17];
  const float* bq_n2 = (const float*)d_in[18];
  const float* Wv_n2 = (const float*)d_in[19];
  const float* bv_n2 = (const float*)d_in[20];
  const float* Wa_n2 = (const float*)d_in[21];
  const float* ba_n2 = (const float*)d_in[22];
  const float* skip_n2 = (const float*)d_in[23];
  const float* a_rel_12 = (const float*)d_in[24];
  const float* m_rel_12 = (const float*)d_in[25];
  const float* p_rel_12 = (const float*)d_in[26];
  const float* a_rel_21 = (const float*)d_in[27];
  const float* m_rel_21 = (const float*)d_in[28];
  const float* p_rel_21 = (const float*)d_in[29];
  const int*   ei_12 = (const int*)d_in[30];
  const int*   ei_21 = (const int*)d_in[31];
  const int*   edge_index = (const int*)d_in[32];
  float* y = (float*)d_out;

  // ---- workspace carve-up (float units) ----
  const size_t NF = (size_t)PN1 * 128;       // 1,280,000
  float* ws = (float*)d_ws;
  float* x1   = ws + 0 * NF;
  float* x2   = ws + 1 * NF;
  float* q1   = ws + 2 * NF;
  float* q2   = ws + 3 * NF;
  float* agg1 = ws + 4 * NF;
  float* agg2 = ws + 5 * NF;
  unsigned* kv1 = (unsigned*)(ws + 6 * NF);              // [N,128] uints (k/v interleaved bf16)
  unsigned* kv2 = (unsigned*)(ws + 7 * NF);
  ushort_t* Em  = (ushort_t*)(ws + 8 * NF);              // [N1,256] bf16
  ushort_t* Ed  = (ushort_t*)(ws + 8 * NF + 1280000);
  float* WkF1 = ws + 8 * NF + 2560000;  float* bkF1 = WkF1 + 16384;
  float* WvF1 = WkF1 + 16512;           float* bvF1 = WvF1 + 16384;
  float* WkF2 = WvF1 + 16512;           float* bkF2 = WkF2 + 16384;
  float* WvF2 = WkF2 + 16512;           float* bvF2 = WvF2 + 16384;
  int* ip = (int*)(WvF2 + 16512);
  int* rowptr12 = ip;                   // 10016 each
  int* rowptr21 = ip + 10016;
  int* cur12    = ip + 20032;
  int* cur21    = ip + 30048;
  int* deg12    = ip + 40064;
  int* deg21    = ip + 50080;
  int* csr12    = ip + 60096;
  int* csr21    = ip + 60096 + NE12;

  const int NB = (PN1 + GR - 1) / GR;        // 313 blocks per type
  const int EB = (NE12 + 255) / 256;         // 1250

  // ---- CSR build (graph constant across layers) ----
  hipMemsetAsync(deg12, 0, 2 * 10016 * sizeof(int), stream);
  csr_hist2<<<EB, 256, 0, stream>>>(ei_12 + NE12, ei_21 + NE21, deg12, deg21);
  csr_scan2<<<2, 256, 0, stream>>>(deg12, rowptr12, cur12, PN2, NE12,
                                   deg21, rowptr21, cur21, PN1, NE21);
  csr_scatter2<<<EB, 256, 0, stream>>>(ei_12, ei_12 + NE12, cur12, csr12,
                                       ei_21, ei_21 + NE21, cur21, csr21);

  // ---- input projections + relu (both types, one launch) ----
  gemm_dual<<<2 * NB, 256, 0, stream>>>(x_n1, W_in1, b_in1, x1,
                                        x_n2, W_in2, b_in2, x2,
                                        NB, PN1, 0, nullptr, nullptr, nullptr, nullptr, 0);

  for (int l = 0; l < NLAY; ++l) {
    const size_t wo = (size_t)l * 16384;
    const int bo = l * 128;

    fuse_rel4<<<dim3(65, 4), 256, 0, stream>>>(
        Wk_n1 + wo, bk_n1 + bo, a_rel_12 + (size_t)l * 2048,
        Wv_n1 + wo, bv_n1 + bo, m_rel_12 + (size_t)l * 2048,
        Wk_n2 + wo, bk_n2 + bo, a_rel_21 + (size_t)l * 2048,
        Wv_n2 + wo, bv_n2 + bo, m_rel_21 + (size_t)l * 2048,
        WkF1, bkF1, WvF1, bvF1, WkF2, bkF2, WvF2, bvF2);

    kvq_dual<<<2 * NB, 256, 0, stream>>>(
        x1, Wq_n1 + wo, bq_n1 + bo, WkF1, bkF1, WvF1, bvF1, q1, kv1,
        x2, Wq_n2 + wo, bq_n2 + bo, WkF2, bkF2, WvF2, bvF2, q2, kv2, NB, PN1);

    attn_gather2<<<(2 * PN1) / 4, 256, 0, stream>>>(
        rowptr12, csr12, q2, kv1, p_rel_12 + l * NH,
        rowptr21, csr21, q1, kv2, p_rel_21 + l * NH,
        agg2, agg1);

    gemm_dual<<<2 * NB, 256, 0, stream>>>(agg1, Wa_n1 + wo, ba_n1 + bo, x1,
                                          agg2, Wa_n2 + wo, ba_n2 + bo, x2,
                                          NB, PN1, 2, skip_n1 + l, skip_n2 + l, Em, Ed, bo);
  }

  // ---- readout ----
  const int DOT_B = (NEF * 8 + 255) / 256;   // 15625
  edge_dot_bf<<<DOT_B, 256, 0, stream>>>(edge_index, edge_index + NEF, Em, Ed, y, NEF);
}

// Round 8
// 460.665 us; speedup vs baseline: 21.4796x; 1.0948x over previous
//
#include <hip/hip_runtime.h>
#include <cstdint>
#include <cstddef>

typedef unsigned short ushort_t;
typedef __attribute__((ext_vector_type(8))) short bf16x8;
typedef __attribute__((ext_vector_type(4))) float f32x4;

// Problem constants
#define PN1   10000
#define PN2   10000
#define NH    8
#define NLAY  2
#define NE12  320000
#define NE21  320000
#define NEF   500000

// ---------- bf16 helpers (RNE) ----------
__device__ __forceinline__ unsigned f2bf(float f) {
  union { float f; unsigned u; } v; v.f = f;
  return (v.u + 0x7FFFu + ((v.u >> 16) & 1u)) >> 16;
}
__device__ __forceinline__ float bf2f(unsigned s) {
  union { float f; unsigned u; } v; v.u = s << 16; return v.f;
}
union U4 { uint4 u; bf16x8 s; };

// ---------- DPP butterfly: sum over 8 contiguous lanes ----------
__device__ __forceinline__ float dpp_red8(float x) {
  int t;
  t = __builtin_amdgcn_update_dpp(0, __float_as_int(x), 0xB1,  0xf, 0xf, true);
  x += __int_as_float(t);
  t = __builtin_amdgcn_update_dpp(0, __float_as_int(x), 0x4E,  0xf, 0xf, true);
  x += __int_as_float(t);
  t = __builtin_amdgcn_update_dpp(0, __float_as_int(x), 0x141, 0xf, 0xf, true);
  x += __int_as_float(t);
  return x;
}
// neighbor-lane (xor 1) value
__device__ __forceinline__ float dpp_xor1(float x) {
  return __int_as_float(__builtin_amdgcn_update_dpp(0, __float_as_int(x), 0xB1, 0xf, 0xf, true));
}

// ============================================================================
// MFMA GEMM core. Block = 256 thr (4 waves), tile 64 rows x 128 cols, K=128.
// A: fp32 X rows -> bf16 pairs in sA [64][68 uints] (pad 68 => 2-way LDS, free)
// B: pre-converted Wt[n][kpair] bf16 global -> sB [128][68 uints]
// Verified layouts: A[m=lane&15][k=quad*8+j]; B[k=quad*8+j][n=lane&15];
//                   C/D col=lane&15, row=quad*4+reg.
// ============================================================================
#define GB 157   // ceil(10000/64) blocks per node type

__device__ __forceinline__ void stage_A(const float* __restrict__ X, unsigned* sA,
                                        int rowbase, int N, int tid)
{
#pragma unroll
  for (int i = 0; i < 8; ++i) {
    int idx = tid + i * 256;              // 0..2047 float4s
    int r = idx >> 5;                     // 0..63
    int c4 = (idx & 31) << 2;             // 0..124
    int gr = rowbase + r;
    float4 v = make_float4(0.f, 0.f, 0.f, 0.f);
    if (gr < N) v = *(const float4*)(X + (size_t)gr * 128 + c4);
    sA[r * 68 + (c4 >> 1)]     = f2bf(v.x) | (f2bf(v.y) << 16);
    sA[r * 68 + (c4 >> 1) + 1] = f2bf(v.z) | (f2bf(v.w) << 16);
  }
}

__device__ __forceinline__ void stage_B(const unsigned* __restrict__ Wt, unsigned* sB, int tid)
{
#pragma unroll
  for (int i = 0; i < 8; ++i) {
    int idx = tid + i * 256;              // uint4 index 0..2047
    int n = idx >> 4;                     // 0..127
    int k4 = (idx & 15) << 2;             // 0..60
    *(uint4*)&sB[n * 68 + k4] = *(const uint4*)&Wt[(size_t)idx << 2];
  }
}

__device__ __forceinline__ void mfma_compute(const unsigned* sA, const unsigned* sB,
                                             int w, int lane, f32x4 acc[8])
{
#pragma unroll
  for (int ks = 0; ks < 4; ++ks) {
    U4 a; a.u = *(const uint4*)&sA[(w * 16 + (lane & 15)) * 68 + ks * 16 + ((lane >> 4) << 2)];
#pragma unroll
    for (int t = 0; t < 8; ++t) {
      U4 b; b.u = *(const uint4*)&sB[(t * 16 + (lane & 15)) * 68 + ks * 16 + ((lane >> 4) << 2)];
      acc[t] = __builtin_amdgcn_mfma_f32_16x16x32_bf16(a.s, b.s, acc[t], 0, 0, 0);
    }
  }
}

// ---------- single-matrix GEMM: mode 0 = relu; mode 2 = skip-blend + cat ----------
__launch_bounds__(256, 2)
__global__ void mfma_gemm1(const float* __restrict__ X1, const float* __restrict__ X2,
                           const unsigned* __restrict__ W1t, const float* __restrict__ b1,
                           const unsigned* __restrict__ W2t, const float* __restrict__ b2,
                           float* __restrict__ Y1, float* __restrict__ Y2,
                           int nb1, int N, int mode,
                           const float* __restrict__ skip1, const float* __restrict__ skip2,
                           ushort_t* __restrict__ cat1, ushort_t* __restrict__ cat2, int catoff)
{
  __shared__ unsigned sA[64 * 68];
  __shared__ unsigned sB[128 * 68];
  const int tid = threadIdx.x;
  const bool t2 = blockIdx.x >= nb1;
  const int rowbase = (t2 ? blockIdx.x - nb1 : blockIdx.x) * 64;
  const float* X = t2 ? X2 : X1;
  const unsigned* Wt = t2 ? W2t : W1t;
  const float* bias = t2 ? b2 : b1;
  float* Y = t2 ? Y2 : Y1;
  ushort_t* cat = t2 ? cat2 : cat1;

  stage_A(X, sA, rowbase, N, tid);
  stage_B(Wt, sB, tid);
  __syncthreads();

  const int w = tid >> 6, lane = tid & 63;
  f32x4 acc[8];
#pragma unroll
  for (int t = 0; t < 8; ++t) acc[t] = (f32x4){0.f, 0.f, 0.f, 0.f};
  mfma_compute(sA, sB, w, lane, acc);

  float beta = 0.f;
  if (mode == 2) beta = 1.0f / (1.0f + expf(-((t2 ? skip2 : skip1)[0])));
  const int cb = lane & 15;
  const int rq = (lane >> 4) << 2;
#pragma unroll
  for (int t = 0; t < 8; ++t) {
    int c = t * 16 + cb;
    float bv = bias[c];
#pragma unroll
    for (int r = 0; r < 4; ++r) {
      int row = rowbase + w * 16 + rq + r;
      float val = acc[t][r] + bv;
      if (mode == 0) {
        if (row < N) Y[(size_t)row * 128 + c] = fmaxf(val, 0.f);
      } else {
        float xo = (row < N) ? Y[(size_t)row * 128 + c] : 0.f;
        float tv = beta * val + (1.f - beta) * xo;
        if (row < N) Y[(size_t)row * 128 + c] = tv;
        float nb = dpp_xor1(tv);
        if (((lane & 1) == 0) && row < N)
          *(unsigned*)(cat + (size_t)row * 256 + catoff + c) = f2bf(tv) | (f2bf(nb) << 16);
      }
    }
  }
}

// ---------- fused K/V/Q projection (3 matrices, shared A) ----------
__launch_bounds__(256, 2)
__global__ void mfma_kvq(const float* __restrict__ X1, const float* __restrict__ X2,
                         const unsigned* __restrict__ WqT1, const unsigned* __restrict__ WkT1,
                         const unsigned* __restrict__ WvT1,
                         const float* __restrict__ bq1, const float* __restrict__ bk1,
                         const float* __restrict__ bv1,
                         const unsigned* __restrict__ WqT2, const unsigned* __restrict__ WkT2,
                         const unsigned* __restrict__ WvT2,
                         const float* __restrict__ bq2, const float* __restrict__ bk2,
                         const float* __restrict__ bv2,
                         float* __restrict__ q1o, unsigned* __restrict__ kv1,
                         float* __restrict__ q2o, unsigned* __restrict__ kv2,
                         int nb1, int N)
{
  __shared__ unsigned sA[64 * 68];
  __shared__ unsigned sB[128 * 68];
  const int tid = threadIdx.x;
  const bool t2 = blockIdx.x >= nb1;
  const int rowbase = (t2 ? blockIdx.x - nb1 : blockIdx.x) * 64;
  const float* X = t2 ? X2 : X1;
  const unsigned* Wt[3] = { t2 ? WqT2 : WqT1, t2 ? WkT2 : WkT1, t2 ? WvT2 : WvT1 };
  const float* bs[3] = { t2 ? bq2 : bq1, t2 ? bk2 : bk1, t2 ? bv2 : bv1 };
  float* qo = t2 ? q2o : q1o;
  unsigned* kvo = t2 ? kv2 : kv1;

  stage_A(X, sA, rowbase, N, tid);
  const int w = tid >> 6, lane = tid & 63;
  const int cb = lane & 15;
  const int rq = (lane >> 4) << 2;

  for (int j = 0; j < 3; ++j) {
    if (j > 0) __syncthreads();           // previous sB reads complete
    stage_B(Wt[j], sB, tid);
    __syncthreads();                      // A (j=0) + B ready
    f32x4 acc[8];
#pragma unroll
    for (int t = 0; t < 8; ++t) acc[t] = (f32x4){0.f, 0.f, 0.f, 0.f};
    mfma_compute(sA, sB, w, lane, acc);

#pragma unroll
    for (int t = 0; t < 8; ++t) {
      int c = t * 16 + cb;
      float bv = bs[j][c];
#pragma unroll
      for (int r = 0; r < 4; ++r) {
        int row = rowbase + w * 16 + rq + r;
        float val = acc[t][r] + bv;
        if (j == 0) {
          if (row < N) qo[(size_t)row * 128 + c] = val;
        } else {
          float nb = dpp_xor1(val);       // lane^1 partner (same row, col c^1)
          if (((lane & 1) == 0) && row < N) {
            unsigned pk = f2bf(val) | (f2bf(nb) << 16);
            kvo[(size_t)row * 128 + c + (j == 1 ? 0 : 1)] = pk;
          }
        }
      }
    }
  }
}

// ---------- static weight convert: fp32 W[128k][128n] -> Wt[n][kpair] bf16 ----------
__global__ void w2bf10(const float* W_in1, const float* W_in2,
                       const float* Wq_n1, const float* Wq_n2,
                       const float* Wa_n1, const float* Wa_n2,
                       unsigned* WinT1, unsigned* WinT2,
                       unsigned* WqT1, unsigned* WqT2,
                       unsigned* WaT1, unsigned* WaT2)
{
  const float* W; unsigned* Wt;
  switch (blockIdx.y) {
    case 0: W = W_in1;          Wt = WinT1;        break;
    case 1: W = W_in2;          Wt = WinT2;        break;
    case 2: W = Wq_n1;          Wt = WqT1;         break;
    case 3: W = Wq_n1 + 16384;  Wt = WqT1 + 8192;  break;
    case 4: W = Wq_n2;          Wt = WqT2;         break;
    case 5: W = Wq_n2 + 16384;  Wt = WqT2 + 8192;  break;
    case 6: W = Wa_n1;          Wt = WaT1;         break;
    case 7: W = Wa_n1 + 16384;  Wt = WaT1 + 8192;  break;
    case 8: W = Wa_n2;          Wt = WaT2;         break;
    default: W = Wa_n2 + 16384; Wt = WaT2 + 8192;  break;
  }
  int idx = blockIdx.x * 256 + threadIdx.x;   // 0..8191
  int n = idx & 127, kp = idx >> 7;
  float a = W[(size_t)(2 * kp) * 128 + n];
  float b = W[(size_t)(2 * kp + 1) * 128 + n];
  Wt[n * 64 + kp] = f2bf(a) | (f2bf(b) << 16);
}

// ---------- fold relation matrices -> fused Wt bf16 + fp32 bias ----------
__global__ void fuse_rel4(const float* Wk1, const float* bk1, const float* a12,
                          const float* Wv1, const float* bv1, const float* m12,
                          const float* Wk2, const float* bk2, const float* a21,
                          const float* Wv2, const float* bv2, const float* m21,
                          unsigned* WkT1, float* bkF1, unsigned* WvT1, float* bvF1,
                          unsigned* WkT2, float* bkF2, unsigned* WvT2, float* bvF2)
{
  const float *W, *b, *rel; unsigned* Wt; float* bf;
  switch (blockIdx.y) {
    case 0:  W = Wk1; b = bk1; rel = a12; Wt = WkT1; bf = bkF1; break;
    case 1:  W = Wv1; b = bv1; rel = m12; Wt = WvT1; bf = bvF1; break;
    case 2:  W = Wk2; b = bk2; rel = a21; Wt = WkT2; bf = bkF2; break;
    default: W = Wv2; b = bv2; rel = m21; Wt = WvT2; bf = bvF2; break;
  }
  int idx = blockIdx.x * 256 + threadIdx.x;
  if (idx < 8192) {
    int n = idx & 127, kp = idx >> 7;
    int h = n >> 4, e = n & 15;
    const float* rr = rel + h * 256;
    const float* s0 = W + (size_t)(2 * kp) * 128 + h * 16;
    const float* s1 = s0 + 128;
    float a0 = 0.f, a1 = 0.f;
#pragma unroll
    for (int d = 0; d < 16; ++d) {
      float rv = rr[d * 16 + e];
      a0 = fmaf(s0[d], rv, a0);
      a1 = fmaf(s1[d], rv, a1);
    }
    Wt[n * 64 + kp] = f2bf(a0) | (f2bf(a1) << 16);
  } else if (idx < 8320) {
    int n = idx - 8192;
    int h = n >> 4, e = n & 15;
    const float* rr = rel + h * 256;
    float a = 0.f;
#pragma unroll
    for (int d = 0; d < 16; ++d) a = fmaf(b[h * 16 + d], rr[d * 16 + e], a);
    bf[n] = a;
  }
}

// ---------- CSR build (both graphs) ----------
__global__ void csr_hist2(const int* __restrict__ dst12, const int* __restrict__ dst21,
                          int* __restrict__ deg12, int* __restrict__ deg21)
{
  int e = blockIdx.x * 256 + threadIdx.x;
  if (e < NE12) atomicAdd(&deg12[dst12[e]], 1);
  if (e < NE21) atomicAdd(&deg21[dst21[e]], 1);
}

__global__ void csr_scan2(const int* __restrict__ degA, int* __restrict__ rowptrA,
                          int* __restrict__ cursorA, int NA, int EA,
                          const int* __restrict__ degB, int* __restrict__ rowptrB,
                          int* __restrict__ cursorB, int NB, int EB)
{
  const int* deg = blockIdx.x ? degB : degA;
  int* rowptr = blockIdx.x ? rowptrB : rowptrA;
  int* cursor = blockIdx.x ? cursorB : cursorA;
  const int N = blockIdx.x ? NB : NA;
  const int E = blockIdx.x ? EB : EA;
  __shared__ int part[256];
  const int t = threadIdx.x;
  const int chunk = (N + 255) / 256;
  const int b = t * chunk;
  const int e = (b + chunk < N) ? b + chunk : N;
  int s = 0;
  for (int i = b; i < e; ++i) s += deg[i];
  part[t] = s;
  __syncthreads();
  if (t == 0) {
    int run = 0;
    for (int i = 0; i < 256; ++i) { int v = part[i]; part[i] = run; run += v; }
  }
  __syncthreads();
  int run = part[t];
  for (int i = b; i < e; ++i) { rowptr[i] = run; cursor[i] = run; run += deg[i]; }
  if (t == 0) rowptr[N] = E;
}

__global__ void csr_scatter2(const int* __restrict__ src12, const int* __restrict__ dst12,
                             int* __restrict__ cur12, int* __restrict__ csr12,
                             const int* __restrict__ src21, const int* __restrict__ dst21,
                             int* __restrict__ cur21, int* __restrict__ csr21)
{
  int e = blockIdx.x * 256 + threadIdx.x;
  if (e < NE12) { int p = atomicAdd(&cur12[dst12[e]], 1); csr12[p] = src12[e]; }
  if (e < NE21) { int p = atomicAdd(&cur21[dst21[e]], 1); csr21[p] = src21[e]; }
}

// ---------- fused gather attention (unchanged from R7) ----------
__launch_bounds__(256)
__global__ void attn_gather2(const int* __restrict__ rowptr12, const int* __restrict__ csr12,
                             const float* __restrict__ q2, const unsigned* __restrict__ kv1,
                             const float* __restrict__ pr12,
                             const int* __restrict__ rowptr21, const int* __restrict__ csr21,
                             const float* __restrict__ q1, const unsigned* __restrict__ kv2,
                             const float* __restrict__ pr21,
                             float* __restrict__ agg2, float* __restrict__ agg1)
{
  const int wid = (blockIdx.x * 256 + threadIdx.x) >> 6;
  const int lane = threadIdx.x & 63;
  const bool dirB = wid >= PN2;
  const int d = __builtin_amdgcn_readfirstlane(dirB ? wid - PN2 : wid);
  const int* rowptr = dirB ? rowptr21 : rowptr12;
  const int* csr    = dirB ? csr21 : csr12;
  const float* q    = dirB ? q1 : q2;
  const unsigned* kv = dirB ? kv2 : kv1;
  const float* prel = dirB ? pr21 : pr12;
  float* agg = dirB ? agg1 : agg2;

  const int h = lane >> 3;
  const float2 qv = *(const float2*)(q + (size_t)d * 128 + 2 * lane);
  const float pr = prel[h] * 0.25f;
  const int beg = __builtin_amdgcn_readfirstlane(rowptr[d]);
  const int end = __builtin_amdgcn_readfirstlane(rowptr[d + 1]);
  const int co = 2 * lane;

  float ssum = 0.f, a0 = 0.f, a1 = 0.f;

  uint2 buf[8];
#pragma unroll
  for (int j = 0; j < 8; ++j) {
    buf[j] = make_uint2(0u, 0u);
    if (beg + j < end) {
      int s = __builtin_amdgcn_readfirstlane(csr[beg + j]);
      buf[j] = *(const uint2*)(kv + (size_t)s * 128 + co);
    }
  }

  for (int i = beg; i < end; i += 8) {
    uint2 cur[8];
#pragma unroll
    for (int j = 0; j < 8; ++j) cur[j] = buf[j];
#pragma unroll
    for (int j = 0; j < 8; ++j) {
      int idx = i + 8 + j;
      if (idx < end) {
        int s = __builtin_amdgcn_readfirstlane(csr[idx]);
        buf[j] = *(const uint2*)(kv + (size_t)s * 128 + co);
      }
    }
    float p[8], ex[8];
#pragma unroll
    for (int j = 0; j < 8; ++j)
      p[j] = fmaf(qv.x, bf2f(cur[j].x & 0xffffu), qv.y * bf2f(cur[j].x >> 16));
#pragma unroll
    for (int j = 0; j < 8; ++j) p[j] = dpp_red8(p[j]);
#pragma unroll
    for (int j = 0; j < 8; ++j)
      ex[j] = (i + j < end) ? __expf(p[j] * pr) : 0.f;
    ssum += ((ex[0] + ex[1]) + (ex[2] + ex[3])) + ((ex[4] + ex[5]) + (ex[6] + ex[7]));
#pragma unroll
    for (int j = 0; j < 8; ++j) {
      a0 = fmaf(ex[j], bf2f(cur[j].y & 0xffffu), a0);
      a1 = fmaf(ex[j], bf2f(cur[j].y >> 16),     a1);
    }
  }

  const float inv = 1.0f / (ssum + 1e-16f);
  float o0 = a0 * inv;
  float o1 = a1 * inv;
  o0 = 0.5f * o0 * (1.f + erff(o0 * 0.70710678118654752f));
  o1 = 0.5f * o1 * (1.f + erff(o1 * 0.70710678118654752f));
  float2 out; out.x = o0; out.y = o1;
  *(float2*)(agg + (size_t)d * 128 + co) = out;
}

// ---------- readout on bf16 Em/Ed (unchanged from R7) ----------
__launch_bounds__(256)
__global__ void edge_dot_bf(const int* __restrict__ mi, const int* __restrict__ di,
                            const ushort_t* __restrict__ Em, const ushort_t* __restrict__ Ed,
                            float* __restrict__ y, int E)
{
  int t = blockIdx.x * 256 + threadIdx.x;
  int e = t >> 3;
  int l = t & 7;
  if (e >= E) return;
  int m = mi[e], d = di[e];
  const uint4* A = (const uint4*)(Em + (size_t)m * 256);
  const uint4* B = (const uint4*)(Ed + (size_t)d * 256);
  float acc = 0.f;
#pragma unroll
  for (int i = 0; i < 4; ++i) {
    uint4 a = A[l + 8 * i];
    uint4 b = B[l + 8 * i];
    acc = fmaf(bf2f(a.x & 0xffffu), bf2f(b.x & 0xffffu), acc);
    acc = fmaf(bf2f(a.x >> 16),     bf2f(b.x >> 16),     acc);
    acc = fmaf(bf2f(a.y & 0xffffu), bf2f(b.y & 0xffffu), acc);
    acc = fmaf(bf2f(a.y >> 16),     bf2f(b.y >> 16),     acc);
    acc = fmaf(bf2f(a.z & 0xffffu), bf2f(b.z & 0xffffu), acc);
    acc = fmaf(bf2f(a.z >> 16),     bf2f(b.z >> 16),     acc);
    acc = fmaf(bf2f(a.w & 0xffffu), bf2f(b.w & 0xffffu), acc);
    acc = fmaf(bf2f(a.w >> 16),     bf2f(b.w >> 16),     acc);
  }
  acc = dpp_red8(acc);
  if (l == 0) y[e] = acc;
}

// ---------- launch ----------
extern "C" void kernel_launch(void* const* d_in, const int* in_sizes, int n_in,
                              void* d_out, int out_size, void* d_ws, size_t ws_size,
                              hipStream_t stream)
{
  const float* x_n1  = (const float*)d_in[0];
  const float* x_n2  = (const float*)d_in[1];
  const float* W_in1 = (const float*)d_in[2];
  const float* b_in1 = (const float*)d_in[3];
  const float* W_in2 = (const float*)d_in[4];
  const float* b_in2 = (const float*)d_in[5];
  const float* Wk_n1 = (const float*)d_in[6];
  const float* bk_n1 = (const float*)d_in[7];
  const float* Wq_n1 = (const float*)d_in[8];
  const float* bq_n1 = (const float*)d_in[9];
  const float* Wv_n1 = (const float*)d_in[10];
  const float* bv_n1 = (const float*)d_in[11];
  const float* Wa_n1 = (const float*)d_in[12];
  const float* ba_n1 = (const float*)d_in[13];
  const float* skip_n1 = (const float*)d_in[14];
  const float* Wk_n2 = (const float*)d_in[15];
  const float* bk_n2 = (const float*)d_in[16];
  const float* Wq_n2 = (const float*)d_in[17];
  const float* bq_n2 = (const float*)d_in[18];
  const float* Wv_n2 = (const float*)d_in[19];
  const float* bv_n2 = (const float*)d_in[20];
  const float* Wa_n2 = (const float*)d_in[21];
  const float* ba_n2 = (const float*)d_in[22];
  const float* skip_n2 = (const float*)d_in[23];
  const float* a_rel_12 = (const float*)d_in[24];
  const float* m_rel_12 = (const float*)d_in[25];
  const float* p_rel_12 = (const float*)d_in[26];
  const float* a_rel_21 = (const float*)d_in[27];
  const float* m_rel_21 = (const float*)d_in[28];
  const float* p_rel_21 = (const float*)d_in[29];
  const int*   ei_12 = (const int*)d_in[30];
  const int*   ei_21 = (const int*)d_in[31];
  const int*   edge_index = (const int*)d_in[32];
  float* y = (float*)d_out;

  // ---- workspace carve-up (float units) ----
  const size_t NF = (size_t)PN1 * 128;       // 1,280,000
  float* ws = (float*)d_ws;
  float* x1   = ws + 0 * NF;
  float* x2   = ws + 1 * NF;
  float* q1   = ws + 2 * NF;
  float* q2   = ws + 3 * NF;
  float* agg1 = ws + 4 * NF;
  float* agg2 = ws + 5 * NF;
  unsigned* kv1 = (unsigned*)(ws + 6 * NF);
  unsigned* kv2 = (unsigned*)(ws + 7 * NF);
  ushort_t* Em  = (ushort_t*)(ws + 8 * NF);
  ushort_t* Ed  = (ushort_t*)(ws + 8 * NF + 1280000);
  unsigned* wb = (unsigned*)(ws + 8 * NF + 2560000);
  unsigned* WkT1 = wb;            float* bkF1 = (float*)(wb + 8192);
  unsigned* WvT1 = wb + 8320;     float* bvF1 = (float*)(wb + 16512);
  unsigned* WkT2 = wb + 16640;    float* bkF2 = (float*)(wb + 24832);
  unsigned* WvT2 = wb + 24960;    float* bvF2 = (float*)(wb + 33152);
  unsigned* WinT1 = wb + 33280;
  unsigned* WinT2 = wb + 41472;
  unsigned* WqT1  = wb + 49664;   // 2 layers x 8192
  unsigned* WqT2  = wb + 66048;
  unsigned* WaT1  = wb + 82432;
  unsigned* WaT2  = wb + 98816;
  int* ip = (int*)(wb + 115200);
  int* rowptr12 = ip;
  int* rowptr21 = ip + 10016;
  int* cur12    = ip + 20032;
  int* cur21    = ip + 30048;
  int* deg12    = ip + 40064;
  int* deg21    = ip + 50080;
  int* csr12    = ip + 60096;
  int* csr21    = ip + 60096 + NE12;

  const int EB = (NE12 + 255) / 256;

  // ---- CSR build ----
  hipMemsetAsync(deg12, 0, 2 * 10016 * sizeof(int), stream);
  csr_hist2<<<EB, 256, 0, stream>>>(ei_12 + NE12, ei_21 + NE21, deg12, deg21);
  csr_scan2<<<2, 256, 0, stream>>>(deg12, rowptr12, cur12, PN2, NE12,
                                   deg21, rowptr21, cur21, PN1, NE21);
  csr_scatter2<<<EB, 256, 0, stream>>>(ei_12, ei_12 + NE12, cur12, csr12,
                                       ei_21, ei_21 + NE21, cur21, csr21);

  // ---- static weight conversion (10 matrices) ----
  w2bf10<<<dim3(32, 10), 256, 0, stream>>>(W_in1, W_in2, Wq_n1, Wq_n2, Wa_n1, Wa_n2,
                                           WinT1, WinT2, WqT1, WqT2, WaT1, WaT2);

  // ---- input projections + relu ----
  mfma_gemm1<<<2 * GB, 256, 0, stream>>>(x_n1, x_n2, WinT1, b_in1, WinT2, b_in2,
                                         x1, x2, GB, PN1, 0,
                                         nullptr, nullptr, nullptr, nullptr, 0);

  for (int l = 0; l < NLAY; ++l) {
    const size_t wo = (size_t)l * 16384;
    const int bo = l * 128;

    fuse_rel4<<<dim3(33, 4), 256, 0, stream>>>(
        Wk_n1 + wo, bk_n1 + bo, a_rel_12 + (size_t)l * 2048,
        Wv_n1 + wo, bv_n1 + bo, m_rel_12 + (size_t)l * 2048,
        Wk_n2 + wo, bk_n2 + bo, a_rel_21 + (size_t)l * 2048,
        Wv_n2 + wo, bv_n2 + bo, m_rel_21 + (size_t)l * 2048,
        WkT1, bkF1, WvT1, bvF1, WkT2, bkF2, WvT2, bvF2);

    mfma_kvq<<<2 * GB, 256, 0, stream>>>(
        x1, x2,
        WqT1 + (size_t)l * 8192, WkT1, WvT1, bq_n1 + bo, bkF1, bvF1,
        WqT2 + (size_t)l * 8192, WkT2, WvT2, bq_n2 + bo, bkF2, bvF2,
        q1, kv1, q2, kv2, GB, PN1);

    attn_gather2<<<(2 * PN1) / 4, 256, 0, stream>>>(
        rowptr12, csr12, q2, kv1, p_rel_12 + l * NH,
        rowptr21, csr21, q1, kv2, p_rel_21 + l * NH,
        agg2, agg1);

    mfma_gemm1<<<2 * GB, 256, 0, stream>>>(
        agg1, agg2, WaT1 + (size_t)l * 8192, ba_n1 + bo,
        WaT2 + (size_t)l * 8192, ba_n2 + bo,
        x1, x2, GB, PN1, 2, skip_n1 + l, skip_n2 + l, Em, Ed, bo);
  }

  // ---- readout ----
  const int DOT_B = (NEF * 8 + 255) / 256;
  edge_dot_bf<<<DOT_B, 256, 0, stream>>>(edge_index, edge_index + NEF, Em, Ed, y, NEF);
}